// Round 10
// baseline (234.809 us; speedup 1.0000x reference)
//
#include <hip/hip_runtime.h>
#include <math.h>

#define BATCH 512
#define SEQ   256
#define DIM   256
#define NHEAD 8
#define DFF   1024
#define NT    512   // threads per block
#define NW    8     // waves per block

// ---------- helpers ----------

__device__ __forceinline__ float dot4f(float4 a, float4 b) {
  return fmaf(a.x, b.x, fmaf(a.y, b.y, fmaf(a.z, b.z, a.w * b.w)));
}

// Reduce 8 independent partial sums across 64 lanes simultaneously.
// Args (a..h); output: 8-lane group g = lane>>3 holds:
//   g0:a g1:e g2:c g3:g g4:b g5:f g6:d g7:h   (all lanes of the group)
__device__ __forceinline__ float fold8(int lane,
    float a, float b, float c, float d,
    float e, float f, float g, float h) {
  float z0 = (lane & 32) ? b : a;
  float t0 = (lane & 32) ? a : b;
  z0 += __shfl_xor(t0, 32, 64);
  float z1 = (lane & 32) ? d : c;
  float t1 = (lane & 32) ? c : d;
  z1 += __shfl_xor(t1, 32, 64);
  float z2 = (lane & 32) ? f : e;
  float t2 = (lane & 32) ? e : f;
  z2 += __shfl_xor(t2, 32, 64);
  float z3 = (lane & 32) ? h : g;
  float t3 = (lane & 32) ? g : h;
  z3 += __shfl_xor(t3, 32, 64);
  float w01 = (lane & 16) ? z1 : z0;
  float s01 = (lane & 16) ? z0 : z1;
  w01 += __shfl_xor(s01, 16, 64);
  float w23 = (lane & 16) ? z3 : z2;
  float s23 = (lane & 16) ? z2 : z3;
  w23 += __shfl_xor(s23, 16, 64);
  float u = (lane & 8) ? w23 : w01;
  float t = (lane & 8) ? w01 : w23;
  u += __shfl_xor(t, 8, 64);
  u += __shfl_xor(u, 4, 64);
  u += __shfl_xor(u, 2, 64);
  u += __shfl_xor(u, 1, 64);
  return u;
}

// Reduce 4 independent partials. 16-lane group g = lane>>4 holds:
//   g0:p0 g1:p2 g2:p1 g3:p3  -> row offset [0,2,1,3][g]
__device__ __forceinline__ float fold4(int lane, float p0, float p1, float p2, float p3) {
  float za = (lane & 32) ? p1 : p0;
  float ta = (lane & 32) ? p0 : p1;
  za += __shfl_xor(ta, 32, 64);
  float zb = (lane & 32) ? p3 : p2;
  float tb = (lane & 32) ? p2 : p3;
  zb += __shfl_xor(tb, 32, 64);
  float u = (lane & 16) ? zb : za;
  float t = (lane & 16) ? za : zb;
  u += __shfl_xor(t, 16, 64);
  u += __shfl_xor(u, 8, 64);
  u += __shfl_xor(u, 4, 64);
  u += __shfl_xor(u, 2, 64);
  u += __shfl_xor(u, 1, 64);
  return u;
}

// block sum over 8 waves; ALL 512 threads must call
__device__ __forceinline__ float block_sum8(float v, float* red) {
  #pragma unroll
  for (int off = 32; off > 0; off >>= 1) v += __shfl_xor(v, off, 64);
  __syncthreads();
  if ((threadIdx.x & 63) == 0) red[threadIdx.x >> 6] = v;
  __syncthreads();
  float s = 0.f;
  #pragma unroll
  for (int i = 0; i < NW; ++i) s += red[i];
  return s;
}

// 8 rows (base + {0..56 step 8}) x K=256 dot + fold; group g writes row base+8g.
template <int LDW>
__device__ __forceinline__ float rows8_fold(const float* __restrict__ W, int base,
                                            int lane, float4 x) {
  const float* wp = W + (size_t)base * LDW + lane * 4;
  float4 wa = *(const float4*)(wp);
  float4 wb = *(const float4*)(wp + 32 * LDW);
  float4 wc = *(const float4*)(wp + 16 * LDW);
  float4 wd = *(const float4*)(wp + 48 * LDW);
  float4 we = *(const float4*)(wp + 8 * LDW);
  float4 wf = *(const float4*)(wp + 40 * LDW);
  float4 wg = *(const float4*)(wp + 24 * LDW);
  float4 wh = *(const float4*)(wp + 56 * LDW);
  return fold8(lane, dot4f(wa, x), dot4f(wb, x), dot4f(wc, x), dot4f(wd, x),
                     dot4f(we, x), dot4f(wf, x), dot4f(wg, x), dot4f(wh, x));
}

struct Buf {
  float sc[2048];     // w~ [d][h] -> scores [h][s] -> att [s][h] -> u [h][d] -> ffb -> z1/a0/a1
  float pe[SEQ];
  float srcl[DIM];
  float qv[DIM];      // q -> tv(LN1) -> tv(LN2)
  float ao[DIM];
  float h1[DIM];      // h1 -> d1
  float h2[DIM];
  float xr[DIM];
  float znin[260];
  float fa[280];
  float znv[20];
  float cb[8];
  float scA[9 * 8];
  float scZ[20 * 8];
  float mHJ[8 * 8];
  float biasO8[8];
  float wsum8[8];
  float attA[8 * 9];
  float attZ[8 * 20];
  float oAcc[8 * 7];
  float peAcc8[8];
  int   Xa[SEQ];
  int   Xz[SEQ];
  float Xo[SEQ * 7];
};

// ---------- fused kernel: ONE batch element per 512-thread block ----------
// 512 blocks -> 2 independent blocks/CU (LDS ~40KB*2 <= 160KB): co-resident
// blocks overlap each other's barrier/latency stalls. fold8 GEMV: 8 rows per
// wave-iter, one 11-shuffle butterfly reduces all 8 outputs.

__global__ __launch_bounds__(NT, 4) void nmstpp_fused(
    const int*   __restrict__ X,
    const float* __restrict__ emb_act,
    const float* __restrict__ emb_zone,
    const float* __restrict__ lin0_w,
    const float* __restrict__ lin0_b,
    const float* __restrict__ qkv_w,
    const float* __restrict__ qkv_b,
    const float* __restrict__ attn_o_w,
    const float* __restrict__ attn_o_b,
    const float* __restrict__ ln1_g, const float* __restrict__ ln1_b,
    const float* __restrict__ ff1_w,
    const float* __restrict__ ff1_b,
    const float* __restrict__ ff2_w,
    const float* __restrict__ ff2_b,
    const float* __restrict__ ln2_g, const float* __restrict__ ln2_b,
    const float* __restrict__ relu_w,
    const float* __restrict__ relu_b,
    const float* __restrict__ dT_w,
    const float* __restrict__ dT_b,
    const float* __restrict__ lindT_w,
    const float* __restrict__ lindT_b,
    const float* __restrict__ zn_w,
    const float* __restrict__ zn_b,
    const float* __restrict__ linzn_w,
    const float* __restrict__ linzn_b,
    const float* __restrict__ act0_w,
    const float* __restrict__ act0_b,
    const float* __restrict__ act1_w,
    const float* __restrict__ act1_b,
    const float* __restrict__ linact_w,
    const float* __restrict__ linact_b,
    float* __restrict__ out)
{
  const int tid  = threadIdx.x;
  const int wid  = tid >> 6;          // 0..7
  const int lane = tid & 63;
  const int b    = blockIdx.x;
  const int hb4  = (tid >> 8) * 4;    // head-half: threads<256 -> heads 0-3, else 4-7
  const int dd   = tid & 255;         // channel/position for 256-wide split phases

  __shared__ alignas(16) Buf s;
  __shared__ float embA[9 * 65];
  __shared__ float embZ[20 * 65];
  __shared__ float l0w[128 * 7];
  __shared__ float l0b[128];
  __shared__ float red[NW];

  // ---- phase 0: stage tables + X / pe ----
  for (int i = tid; i < 9 * 64;  i += NT) embA[(i >> 6) * 65 + (i & 63)] = emb_act[i];
  for (int i = tid; i < 20 * 64; i += NT) embZ[(i >> 6) * 65 + (i & 63)] = emb_zone[i];
  for (int i = tid; i < 128 * 7; i += NT) l0w[i] = lin0_w[i];
  if (tid < 128) l0b[tid] = lin0_b[tid];
  if (tid < SEQ) {
    const int* xrow = X + (b * SEQ + tid) * 9;
    s.Xa[tid] = xrow[0];
    s.Xz[tid] = xrow[1];
    #pragma unroll
    for (int j = 0; j < 7; ++j) s.Xo[tid * 7 + j] = (float)xrow[2 + j];
    float ex  = (float)(2 * tid) / (float)SEQ;
    float ang = (float)b * exp2f(-ex * 6.643856189774724f);  // 100^-ex
    s.pe[tid] = ((tid & 1) == 0) ? sinf(ang) : cosf(ang);
  }
  __syncthreads();

  // ---- phase 1: src at last position ----
  if (tid < DIM) {
    int av = s.Xa[SEQ - 1], zv = s.Xz[SEQ - 1];
    float v;
    if (tid < 64)        v = embA[av * 65 + tid];
    else if (tid < 128)  v = embZ[zv * 65 + (tid - 64)];
    else {
      const float* lr = l0w + (tid - 128) * 7;
      float acc = l0b[tid - 128];
      #pragma unroll
      for (int j = 0; j < 7; ++j) acc = fmaf(lr[j], s.Xo[(SEQ - 1) * 7 + j], acc);
      v = acc;
    }
    s.srcl[tid] = v + s.pe[SEQ - 1];
  }
  __syncthreads();

  // ---- phase 2: q = Wq @ srcl + bq ----
  {
    float4 x = *(const float4*)(s.srcl + lane * 4);
    for (int idx = wid; idx < 32; idx += NW) {
      int base = (idx >> 3) * 64 + (idx & 7);
      float u = rows8_fold<256>(qkv_w, base, lane, x);
      if ((lane & 7) == 0) {
        int rr = base + (lane >> 3) * 8;
        s.qv[rr] = qkv_b[rr] + u;
      }
    }
  }
  __syncthreads();

  // ---- phase 3: w~[d][h] (column sweep; 4 heads per half) ----
  {
    const float inv = 0.17677669529663687f;  // 1/sqrt(32)
    float acc[4] = {};
    for (int c = 0; c < 32; ++c) {
      #pragma unroll
      for (int hh = 0; hh < 4; ++hh) {
        int h = hb4 + hh;
        acc[hh] = fmaf(s.qv[h * 32 + c], qkv_w[(size_t)(DIM + h * 32 + c) * DIM + dd], acc[hh]);
      }
    }
    #pragma unroll
    for (int hh = 0; hh < 4; ++hh) s.sc[dd * 8 + hb4 + hh] = acc[hh] * inv;
  }
  __syncthreads();

  // ---- phase 3.5: collapse scores into lookup tables ----
  if (tid < 312) {
    if (tid < 296) {
      int h = tid / 37, k = tid - h * 37;
      if (k < 9) {
        float acc = 0.f;
        for (int c = 0; c < 64; ++c) acc = fmaf(s.sc[c * 8 + h], embA[k * 65 + c], acc);
        s.scA[k * 8 + h] = acc;
      } else if (k < 29) {
        int z = k - 9; float acc = 0.f;
        for (int c = 0; c < 64; ++c) acc = fmaf(s.sc[(64 + c) * 8 + h], embZ[z * 65 + c], acc);
        s.scZ[z * 8 + h] = acc;
      } else if (k < 36) {
        int j = k - 29; float acc = 0.f;
        for (int kk = 0; kk < 128; ++kk) acc = fmaf(s.sc[(128 + kk) * 8 + h], l0w[kk * 7 + j], acc);
        s.mHJ[h * 8 + j] = acc;
      } else {
        float acc = 0.f;
        for (int c = 0; c < 256; ++c) acc += s.sc[c * 8 + h];
        s.wsum8[h] = acc;
      }
    } else if (tid < 304) {
      int h = tid - 296; float acc = 0.f;
      for (int kk = 0; kk < 128; ++kk) acc = fmaf(s.sc[(128 + kk) * 8 + h], l0b[kk], acc);
      s.biasO8[h] = acc;
    } else {
      int h = tid - 304; float acc = 0.f;
      for (int c = 0; c < 32; ++c) acc += s.qv[h * 32 + c] * qkv_b[DIM + h * 32 + c];
      s.cb[h] = acc * 0.17677669529663687f;
    }
  }
  __syncthreads();

  // ---- phase 4: scores via tables (thread = (position, head-half)) ----
  {
    const int sp = dd;
    int av = s.Xa[sp], zv = s.Xz[sp];
    float o[7];
    #pragma unroll
    for (int j = 0; j < 7; ++j) o[j] = s.Xo[sp * 7 + j];
    float pes = s.pe[sp];
    #pragma unroll
    for (int hh = 0; hh < 4; ++hh) {
      int h = hb4 + hh;
      float acc = s.scA[av * 8 + h] + s.scZ[zv * 8 + h] + s.biasO8[h] + s.cb[h];
      acc = fmaf(pes, s.wsum8[h], acc);
      #pragma unroll
      for (int j = 0; j < 7; ++j) acc = fmaf(s.mHJ[h * 8 + j], o[j], acc);
      s.sc[h * SEQ + sp] = acc;
    }
  }
  __syncthreads();

  // ---- phase 5: softmax, wave-per-head, in-place transpose ----
  {
    const int h = wid;
    float vals[4];
    float m = -1e30f;
    #pragma unroll
    for (int i = 0; i < 4; ++i) {
      vals[i] = s.sc[h * SEQ + lane * 4 + i];
      m = fmaxf(m, vals[i]);
    }
    #pragma unroll
    for (int off = 32; off > 0; off >>= 1) m = fmaxf(m, __shfl_xor(m, off, 64));
    float lsum = 0.f;
    #pragma unroll
    for (int i = 0; i < 4; ++i) { vals[i] = expf(vals[i] - m); lsum += vals[i]; }
    #pragma unroll
    for (int off = 32; off > 0; off >>= 1) lsum += __shfl_xor(lsum, off, 64);
    float rinv = 1.0f / lsum;
    __syncthreads();   // everyone done reading sc before transpose-overwrite
    #pragma unroll
    for (int i = 0; i < 4; ++i) s.sc[(lane * 4 + i) * 8 + h] = vals[i] * rinv;
  }
  __syncthreads();

  // ---- phase 6a: attention-weighted histograms / moments ----
  if (tid < 296) {
    int h = tid / 37, k = tid - h * 37;
    float acc = 0.f;
    if (k < 29) {
      int mybin = (k < 9) ? k : (k - 9);
      const int* bins = (k < 9) ? s.Xa : s.Xz;
      for (int sp = 0; sp < SEQ; ++sp) {
        float at = s.sc[sp * 8 + h];
        acc += (bins[sp] == mybin) ? at : 0.f;
      }
      if (k < 9) s.attA[h * 9 + k] = acc; else s.attZ[h * 20 + (k - 9)] = acc;
    } else if (k < 36) {
      int j = k - 29;
      for (int sp = 0; sp < SEQ; ++sp) acc = fmaf(s.sc[sp * 8 + h], s.Xo[sp * 7 + j], acc);
      s.oAcc[h * 7 + j] = acc;
    } else {
      for (int sp = 0; sp < SEQ; ++sp) acc = fmaf(s.sc[sp * 8 + h], s.pe[sp], acc);
      s.peAcc8[h] = acc;
    }
  }
  __syncthreads();

  // ---- phase 6b: reconstruct u[h][d] (4 heads per half) ----
  {
    float acc[4];
    #pragma unroll
    for (int hh = 0; hh < 4; ++hh) acc[hh] = s.peAcc8[hb4 + hh];
    if (dd < 64) {
      for (int a = 0; a < 9; ++a) {
        float ev = embA[a * 65 + dd];
        #pragma unroll
        for (int hh = 0; hh < 4; ++hh) acc[hh] = fmaf(s.attA[(hb4 + hh) * 9 + a], ev, acc[hh]);
      }
    } else if (dd < 128) {
      int d2 = dd - 64;
      for (int z = 0; z < 20; ++z) {
        float ev = embZ[z * 65 + d2];
        #pragma unroll
        for (int hh = 0; hh < 4; ++hh) acc[hh] = fmaf(s.attZ[(hb4 + hh) * 20 + z], ev, acc[hh]);
      }
    } else {
      int kk = dd - 128;
      #pragma unroll
      for (int j = 0; j < 7; ++j) {
        float ov = l0w[kk * 7 + j];
        #pragma unroll
        for (int hh = 0; hh < 4; ++hh) acc[hh] = fmaf(s.oAcc[(hb4 + hh) * 7 + j], ov, acc[hh]);
      }
      #pragma unroll
      for (int hh = 0; hh < 4; ++hh) acc[hh] += l0b[kk];
    }
    #pragma unroll
    for (int hh = 0; hh < 4; ++hh) s.sc[(hb4 + hh) * DIM + dd] = acc[hh];
  }
  __syncthreads();

  // ---- phase 7: ao = Wv @ u + bv (rows of head h use u[h]; 2 heads per call) ----
  for (int idx = wid; idx < 32; idx += NW) {
    int c = idx >> 3;
    int base = c * 64 + (idx & 7);
    float4 xlo = *(const float4*)(s.sc + (2 * c)     * DIM + lane * 4);
    float4 xhi = *(const float4*)(s.sc + (2 * c + 1) * DIM + lane * 4);
    const float* wp = qkv_w + (size_t)(2 * DIM + base) * DIM + lane * 4;
    float4 wa = *(const float4*)(wp);
    float4 wb = *(const float4*)(wp + 32 * DIM);
    float4 wc = *(const float4*)(wp + 16 * DIM);
    float4 wd = *(const float4*)(wp + 48 * DIM);
    float4 we = *(const float4*)(wp + 8 * DIM);
    float4 wf = *(const float4*)(wp + 40 * DIM);
    float4 wg = *(const float4*)(wp + 24 * DIM);
    float4 wh = *(const float4*)(wp + 56 * DIM);
    // offsets {0,16,8,24} -> head 2c (xlo); {32,48,40,56} -> head 2c+1 (xhi)
    float u = fold8(lane, dot4f(wa, xlo), dot4f(wb, xhi), dot4f(wc, xlo), dot4f(wd, xhi),
                          dot4f(we, xlo), dot4f(wf, xhi), dot4f(wg, xlo), dot4f(wh, xhi));
    if ((lane & 7) == 0) {
      int rr = base + (lane >> 3) * 8;
      s.ao[rr] = qkv_b[2 * DIM + rr] + u;
    }
  }
  __syncthreads();

  // ---- phase 8: tv = srcl + attn_o(ao); h1 = LN1(tv) ----
  {
    float4 x = *(const float4*)(s.ao + lane * 4);
    for (int idx = wid; idx < 32; idx += NW) {
      int base = (idx >> 3) * 64 + (idx & 7);
      float u = rows8_fold<256>(attn_o_w, base, lane, x);
      if ((lane & 7) == 0) {
        int rr = base + (lane >> 3) * 8;
        s.qv[rr] = s.srcl[rr] + attn_o_b[rr] + u;
      }
    }
  }
  __syncthreads();
  {
    float tv = (tid < DIM) ? s.qv[tid] : 0.f;
    float mean = block_sum8(tv, red) * (1.0f / 256.0f);
    float dv = (tid < DIM) ? (tv - mean) : 0.f;
    float var = block_sum8(dv * dv, red) * (1.0f / 256.0f);
    if (tid < DIM) s.h1[tid] = dv / sqrtf(var + 1e-5f) * ln1_g[tid] + ln1_b[tid];
  }
  __syncthreads();

  // ---- phase 9: ffb = relu(ff1 @ h1 + b) (1024 rows) ----
  {
    float4 x = *(const float4*)(s.h1 + lane * 4);
    for (int idx = wid; idx < 128; idx += NW) {
      int base = (idx >> 3) * 64 + (idx & 7);
      float u = rows8_fold<256>(ff1_w, base, lane, x);
      if ((lane & 7) == 0) {
        int rr = base + (lane >> 3) * 8;
        s.sc[rr] = fmaxf(ff1_b[rr] + u, 0.f);
      }
    }
  }
  __syncthreads();

  // ---- phase 10: tv = h1 + ff2 @ ffb + b; h2 = LN2(tv) ----
  for (int idx = wid; idx < 32; idx += NW) {
    int base = (idx >> 3) * 64 + (idx & 7);
    float pa = 0, pb = 0, pc = 0, pd = 0, pe2 = 0, pf = 0, pg = 0, ph = 0;
    #pragma unroll
    for (int kc = 0; kc < 4; ++kc) {
      float4 x = *(const float4*)(s.sc + kc * 256 + lane * 4);
      const float* wp = ff2_w + (size_t)base * DFF + kc * 256 + lane * 4;
      pa += dot4f(*(const float4*)(wp),            x);
      pb += dot4f(*(const float4*)(wp + 32 * DFF), x);
      pc += dot4f(*(const float4*)(wp + 16 * DFF), x);
      pd += dot4f(*(const float4*)(wp + 48 * DFF), x);
      pe2 += dot4f(*(const float4*)(wp + 8 * DFF), x);
      pf += dot4f(*(const float4*)(wp + 40 * DFF), x);
      pg += dot4f(*(const float4*)(wp + 24 * DFF), x);
      ph += dot4f(*(const float4*)(wp + 56 * DFF), x);
    }
    float u = fold8(lane, pa, pb, pc, pd, pe2, pf, pg, ph);
    if ((lane & 7) == 0) {
      int rr = base + (lane >> 3) * 8;
      s.qv[rr] = s.h1[rr] + ff2_b[rr] + u;
    }
  }
  __syncthreads();
  {
    float tv = (tid < DIM) ? s.qv[tid] : 0.f;
    float mean = block_sum8(tv, red) * (1.0f / 256.0f);
    float dv = (tid < DIM) ? (tv - mean) : 0.f;
    float var = block_sum8(dv * dv, red) * (1.0f / 256.0f);
    if (tid < DIM) s.h2[tid] = dv / sqrtf(var + 1e-5f) * ln2_g[tid] + ln2_b[tid];
  }
  __syncthreads();

  // ---- phase 11: xr = relu_w @ h2 + b ----
  {
    float4 x = *(const float4*)(s.h2 + lane * 4);
    for (int idx = wid; idx < 32; idx += NW) {
      int base = (idx >> 3) * 64 + (idx & 7);
      float u = rows8_fold<256>(relu_w, base, lane, x);
      if ((lane & 7) == 0) {
        int rr = base + (lane >> 3) * 8;
        s.xr[rr] = relu_b[rr] + u;
      }
    }
  }
  __syncthreads();

  // ---- phase 12: d1 = dT_w @ xr + b; dT = lindT . d1 + b ----
  {
    float4 x = *(const float4*)(s.xr + lane * 4);
    for (int idx = wid; idx < 32; idx += NW) {
      int base = (idx >> 3) * 64 + (idx & 7);
      float u = rows8_fold<256>(dT_w, base, lane, x);
      if ((lane & 7) == 0) {
        int rr = base + (lane >> 3) * 8;
        s.h1[rr] = dT_b[rr] + u;             // h1 = d1
      }
    }
  }
  __syncthreads();
  float dTv;
  {
    float v = (tid < DIM) ? lindT_w[tid] * s.h1[tid] : 0.f;
    dTv = block_sum8(v, red) + lindT_b[0];
  }

  // ---- phase 13: zn path ----
  if (tid < DIM) { s.znin[1 + tid] = s.xr[tid]; s.fa[21 + tid] = s.xr[tid]; }
  if (tid == 0)  { s.znin[0] = dTv; s.fa[20] = dTv; }
  __syncthreads();
  float* z1 = s.sc + 1024;   // 257 floats
  for (int r0 = 4 * wid; r0 < 257; r0 += 4 * NW) {
    int nrow = 257 - r0; if (nrow > 4) nrow = 4;
    float p0 = 0, p1 = 0, p2 = 0, p3 = 0;
    for (int j = lane; j < 257; j += 64) {
      float xv = s.znin[j];
      const float* wp = zn_w + (size_t)r0 * 257 + j;
      p0 = fmaf(wp[0], xv, p0);
      if (nrow > 1) p1 = fmaf(wp[257], xv, p1);
      if (nrow > 2) p2 = fmaf(wp[2 * 257], xv, p2);
      if (nrow > 3) p3 = fmaf(wp[3 * 257], xv, p3);
    }
    float u = fold4(lane, p0, p1, p2, p3);
    if ((lane & 15) == 0) {
      int g = lane >> 4;
      int rr = r0 + ((g & 1) << 1) + (g >> 1);
      if (rr < 257) z1[rr] = zn_b[rr] + u;
    }
  }
  __syncthreads();
  for (int r0 = 4 * wid; r0 < 20; r0 += 4 * NW) {
    float p0 = 0, p1 = 0, p2 = 0, p3 = 0;
    for (int j = lane; j < 257; j += 64) {
      float xv = z1[j];
      const float* wp = linzn_w + (size_t)r0 * 257 + j;
      p0 = fmaf(wp[0], xv, p0);
      p1 = fmaf(wp[257], xv, p1);
      p2 = fmaf(wp[2 * 257], xv, p2);
      p3 = fmaf(wp[3 * 257], xv, p3);
    }
    float u = fold4(lane, p0, p1, p2, p3);
    if ((lane & 15) == 0) {
      int g = lane >> 4;
      int rr = r0 + ((g & 1) << 1) + (g >> 1);
      if (rr < 20) { float v = linzn_b[rr] + u; s.znv[rr] = v; s.fa[rr] = v; }
    }
  }
  __syncthreads();

  // ---- phase 14: ac = linact @ act1 @ act0 @ fa ----
  float* a0v = s.sc + 1312;  // 277 floats
  for (int r0 = 4 * wid; r0 < 277; r0 += 4 * NW) {
    int nrow = 277 - r0; if (nrow > 4) nrow = 4;
    float p0 = 0, p1 = 0, p2 = 0, p3 = 0;
    for (int j = lane; j < 277; j += 64) {
      float xv = s.fa[j];
      const float* wp = act0_w + (size_t)r0 * 277 + j;
      p0 = fmaf(wp[0], xv, p0);
      if (nrow > 1) p1 = fmaf(wp[277], xv, p1);
      if (nrow > 2) p2 = fmaf(wp[2 * 277], xv, p2);
      if (nrow > 3) p3 = fmaf(wp[3 * 277], xv, p3);
    }
    float u = fold4(lane, p0, p1, p2, p3);
    if ((lane & 15) == 0) {
      int g = lane >> 4;
      int rr = r0 + ((g & 1) << 1) + (g >> 1);
      if (rr < 277) a0v[rr] = act0_b[rr] + u;
    }
  }
  __syncthreads();
  float* a1v = s.sc + 1024;  // z1 dead
  for (int r0 = 4 * wid; r0 < 277; r0 += 4 * NW) {
    int nrow = 277 - r0; if (nrow > 4) nrow = 4;
    float p0 = 0, p1 = 0, p2 = 0, p3 = 0;
    for (int j = lane; j < 277; j += 64) {
      float xv = a0v[j];
      const float* wp = act1_w + (size_t)r0 * 277 + j;
      p0 = fmaf(wp[0], xv, p0);
      if (nrow > 1) p1 = fmaf(wp[277], xv, p1);
      if (nrow > 2) p2 = fmaf(wp[2 * 277], xv, p2);
      if (nrow > 3) p3 = fmaf(wp[3 * 277], xv, p3);
    }
    float u = fold4(lane, p0, p1, p2, p3);
    if ((lane & 15) == 0) {
      int g = lane >> 4;
      int rr = r0 + ((g & 1) << 1) + (g >> 1);
      if (rr < 277) a1v[rr] = act1_b[rr] + u;
    }
  }
  __syncthreads();

  // ---- phase 15: outputs ----
  if (wid < 5) {
    const float* wr = linact_w + (size_t)wid * 277;
    float p = 0.f;
    for (int j = lane; j < 277; j += 64) p = fmaf(wr[j], a1v[j], p);
    #pragma unroll
    for (int off = 32; off > 0; off >>= 1) p += __shfl_xor(p, off, 64);
    if (lane == 0) out[b * 26 + 21 + wid] = linact_b[wid] + p;
  }
  if (tid == 0) out[b * 26] = dTv;
  if (tid < 20) out[b * 26 + 1 + tid] = s.znv[tid];
}

// ---------- launcher ----------

extern "C" void kernel_launch(void* const* d_in, const int* in_sizes, int n_in,
                              void* d_out, int out_size, void* d_ws, size_t ws_size,
                              hipStream_t stream) {
  (void)in_sizes; (void)n_in; (void)d_ws; (void)ws_size; (void)out_size;
  const int*   X        = (const int*)  d_in[0];
  const float* emb_act  = (const float*)d_in[1];
  const float* emb_zone = (const float*)d_in[2];
  const float* lin0_w   = (const float*)d_in[3];
  const float* lin0_b   = (const float*)d_in[4];
  const float* qkv_w    = (const float*)d_in[5];
  const float* qkv_b    = (const float*)d_in[6];
  const float* attn_o_w = (const float*)d_in[7];
  const float* attn_o_b = (const float*)d_in[8];
  const float* ln1_g    = (const float*)d_in[9];
  const float* ln1_b    = (const float*)d_in[10];
  const float* ff1_w    = (const float*)d_in[11];
  const float* ff1_b    = (const float*)d_in[12];
  const float* ff2_w    = (const float*)d_in[13];
  const float* ff2_b    = (const float*)d_in[14];
  const float* ln2_g    = (const float*)d_in[15];
  const float* ln2_b    = (const float*)d_in[16];
  const float* relu_w   = (const float*)d_in[17];
  const float* relu_b   = (const float*)d_in[18];
  const float* dT_w     = (const float*)d_in[19];
  const float* dT_b     = (const float*)d_in[20];
  const float* lindT_w  = (const float*)d_in[21];
  const float* lindT_b  = (const float*)d_in[22];
  const float* zn_w     = (const float*)d_in[23];
  const float* zn_b     = (const float*)d_in[24];
  const float* linzn_w  = (const float*)d_in[25];
  const float* linzn_b  = (const float*)d_in[26];
  const float* act0_w   = (const float*)d_in[27];
  const float* act0_b   = (const float*)d_in[28];
  const float* act1_w   = (const float*)d_in[29];
  const float* act1_b   = (const float*)d_in[30];
  const float* linact_w = (const float*)d_in[31];
  const float* linact_b = (const float*)d_in[32];
  float* out = (float*)d_out;

  nmstpp_fused<<<dim3(BATCH), dim3(NT), 0, stream>>>(
      X, emb_act, emb_zone, lin0_w, lin0_b, qkv_w, qkv_b, attn_o_w, attn_o_b,
      ln1_g, ln1_b, ff1_w, ff1_b, ff2_w, ff2_b, ln2_g, ln2_b,
      relu_w, relu_b, dT_w, dT_b, lindT_w, lindT_b, zn_w, zn_b,
      linzn_w, linzn_b, act0_w, act0_b, act1_w, act1_b, linact_w, linact_b,
      out);
}

// Round 11
// 178.138 us; speedup vs baseline: 1.3181x; 1.3181x over previous
//
#include <hip/hip_runtime.h>
#include <math.h>

#define BATCH 512
#define SEQ   256
#define DIM   256
#define NHEAD 8
#define DFF   1024
#define NT    512   // threads per block
#define NW    8     // waves per block

typedef unsigned short ushort;
typedef unsigned int   uint;

// ---------- bf16 weight image layout in d_ws (ushort units) ----------
#define OFF_QKV   0u          // 768*256   = 196608
#define OFF_AO    196608u     // 256*256   =  65536
#define OFF_FF1   262144u     // 1024*256  = 262144
#define OFF_FF2   524288u     // 256*1024  = 262144
#define OFF_RELU  786432u     // 256*256
#define OFF_DT    851968u     // 256*256
#define OFF_ZN    917504u     // 257*257   =  66049
#define OFF_A0    983553u     // 277*277   =  76729
#define OFF_A1    1060282u    // 277*277
#define CVT_TOTAL 1137011u

// ---------- weight conversion kernel (runs every launch; deterministic) ----------
__global__ __launch_bounds__(512) void cvt_weights(
    const float* __restrict__ qkv, const float* __restrict__ ao,
    const float* __restrict__ ff1, const float* __restrict__ ff2,
    const float* __restrict__ relu, const float* __restrict__ dT,
    const float* __restrict__ zn, const float* __restrict__ a0,
    const float* __restrict__ a1, ushort* __restrict__ ws) {
  uint i = blockIdx.x * 512u + threadIdx.x;
  if (i >= CVT_TOTAL) return;
  const float* src; uint off;
  if      (i < OFF_AO)  { src = qkv;  off = OFF_QKV; }
  else if (i < OFF_FF1) { src = ao;   off = OFF_AO; }
  else if (i < OFF_FF2) { src = ff1;  off = OFF_FF1; }
  else if (i < OFF_RELU){ src = ff2;  off = OFF_FF2; }
  else if (i < OFF_DT)  { src = relu; off = OFF_RELU; }
  else if (i < OFF_ZN)  { src = dT;   off = OFF_DT; }
  else if (i < OFF_A0)  { src = zn;   off = OFF_ZN; }
  else if (i < OFF_A1)  { src = a0;   off = OFF_A0; }
  else                  { src = a1;   off = OFF_A1; }
  uint b = __float_as_uint(src[i - off]);
  uint r = (b + 0x7fffu + ((b >> 16) & 1u)) >> 16;   // round-to-nearest-even
  ws[i] = (ushort)r;
}

// ---------- helpers ----------

__device__ __forceinline__ float bf2f(ushort u) {
  return __uint_as_float(((uint)u) << 16);
}

__device__ __forceinline__ float wave_allred(float v) {
  #pragma unroll
  for (int off = 32; off > 0; off >>= 1) v += __shfl_xor(v, off, 64);
  return v;
}

// Reduce 4 independent partials over a full wave. 16-lane group g = lane>>4
// holds value [0,2,1,3][g].
__device__ __forceinline__ float fold4(int lane, float p0, float p1, float p2, float p3) {
  float za = (lane & 32) ? p1 : p0;
  float ta = (lane & 32) ? p0 : p1;
  za += __shfl_xor(ta, 32, 64);
  float zb = (lane & 32) ? p3 : p2;
  float tb = (lane & 32) ? p2 : p3;
  zb += __shfl_xor(tb, 32, 64);
  float u = (lane & 16) ? zb : za;
  float t = (lane & 16) ? za : zb;
  u += __shfl_xor(t, 16, 64);
  u += __shfl_xor(u, 8, 64);
  u += __shfl_xor(u, 4, 64);
  u += __shfl_xor(u, 2, 64);
  u += __shfl_xor(u, 1, 64);
  return u;
}

// Reduce 8 partials WITHIN each 32-lane half (9 shuffles).
// 4-lane group g=(lane>>2)&7 of each half holds value rev3(g).
__device__ __forceinline__ float fold8h(int lane, const float p[8]) {
  float z0 = (lane & 16) ? p[1] : p[0], y0 = (lane & 16) ? p[0] : p[1];
  z0 += __shfl_xor(y0, 16, 64);
  float z1 = (lane & 16) ? p[3] : p[2], y1 = (lane & 16) ? p[2] : p[3];
  z1 += __shfl_xor(y1, 16, 64);
  float z2 = (lane & 16) ? p[5] : p[4], y2 = (lane & 16) ? p[4] : p[5];
  z2 += __shfl_xor(y2, 16, 64);
  float z3 = (lane & 16) ? p[7] : p[6], y3 = (lane & 16) ? p[6] : p[7];
  z3 += __shfl_xor(y3, 16, 64);
  float w0 = (lane & 8) ? z1 : z0, s0 = (lane & 8) ? z0 : z1;
  w0 += __shfl_xor(s0, 8, 64);
  float w1 = (lane & 8) ? z3 : z2, s1 = (lane & 8) ? z2 : z3;
  w1 += __shfl_xor(s1, 8, 64);
  float u = (lane & 4) ? w1 : w0, t = (lane & 4) ? w0 : w1;
  u += __shfl_xor(t, 4, 64);
  u += __shfl_xor(u, 2, 64);
  u += __shfl_xor(u, 1, 64);
  return u;
}

// Writer lanes for a fold8h burst: (lane&3)==0. Value index iv = rev3(g).
// partial index iv = load*2 + batch; row = base + (lane>>5)*4 + load.
__device__ __forceinline__ bool burst_writer(int lane, int& row_off, int& bsel) {
  if (lane & 3) return false;
  int g = (lane >> 2) & 7;
  int iv = ((g & 1) << 2) | (g & 2) | ((g >> 2) & 1);
  row_off = ((lane >> 5) << 2) + (iv >> 1);
  bsel = iv & 1;
  return true;
}

struct X8 { float4 a, b; };

__device__ __forceinline__ X8 ldx8(const float* __restrict__ x, int lane) {
  int k = (lane & 31) * 8;
  X8 r;
  r.a = *(const float4*)(x + k);
  r.b = *(const float4*)(x + k + 4);
  return r;
}

// 8 bf16 weights (uint4) dotted against both batches' x-slices.
__device__ __forceinline__ void accum8(uint4 w, const X8& x0, const X8& x1,
                                       float& p0, float& p1) {
  float e0 = __uint_as_float(w.x << 16);
  float e1 = __uint_as_float(w.x & 0xffff0000u);
  float e2 = __uint_as_float(w.y << 16);
  float e3 = __uint_as_float(w.y & 0xffff0000u);
  float e4 = __uint_as_float(w.z << 16);
  float e5 = __uint_as_float(w.z & 0xffff0000u);
  float e6 = __uint_as_float(w.w << 16);
  float e7 = __uint_as_float(w.w & 0xffff0000u);
  p0 = fmaf(e0, x0.a.x, p0); p0 = fmaf(e1, x0.a.y, p0);
  p0 = fmaf(e2, x0.a.z, p0); p0 = fmaf(e3, x0.a.w, p0);
  p0 = fmaf(e4, x0.b.x, p0); p0 = fmaf(e5, x0.b.y, p0);
  p0 = fmaf(e6, x0.b.z, p0); p0 = fmaf(e7, x0.b.w, p0);
  p1 = fmaf(e0, x1.a.x, p1); p1 = fmaf(e1, x1.a.y, p1);
  p1 = fmaf(e2, x1.a.z, p1); p1 = fmaf(e3, x1.a.w, p1);
  p1 = fmaf(e4, x1.b.x, p1); p1 = fmaf(e5, x1.b.y, p1);
  p1 = fmaf(e6, x1.b.z, p1); p1 = fmaf(e7, x1.b.w, p1);
}

// one burst: 8 rows (base..base+7) x K-slice of 256 starting at Wb (bf16), 2 batches
__device__ __forceinline__ void burst_acc(const ushort* __restrict__ Wb, int ld, int lane,
                                          const X8& x0, const X8& x1, float p[8]) {
  const ushort* wp = Wb + (size_t)((lane >> 5) * 4) * ld + (lane & 31) * 8;
  uint4 w0 = *(const uint4*)(wp);
  uint4 w1 = *(const uint4*)(wp + ld);
  uint4 w2 = *(const uint4*)(wp + 2 * ld);
  uint4 w3 = *(const uint4*)(wp + 3 * ld);
  accum8(w0, x0, x1, p[0], p[1]);
  accum8(w1, x0, x1, p[2], p[3]);
  accum8(w2, x0, x1, p[4], p[5]);
  accum8(w3, x0, x1, p[6], p[7]);
}

// per-batch sum (waves 0-3 = batch0, 4-7 = batch1); ALL 512 threads call
__device__ __forceinline__ float batch_sum(float v, float* red, int wid, int batch) {
  v = wave_allred(v);
  __syncthreads();
  if ((threadIdx.x & 63) == 0) red[wid] = v;
  __syncthreads();
  const int base = batch * 4;
  return red[base] + red[base + 1] + red[base + 2] + red[base + 3];
}

struct BatchBuf {
  float sc[2048];     // w~ [d][h] -> scores [h][s] -> att [s][h] -> u [h][d] -> ffb -> z1/a0/a1
  float pe[SEQ];
  float srcl[DIM];
  float qv[DIM];      // q -> tv(LN1) -> tv(LN2)
  float ao[DIM];
  float h1[DIM];      // h1 -> d1
  float h2[DIM];
  float xr[DIM];
  float znin[260];
  float fa[280];
  float znv[20];
  float cb[8];
  float scA[9 * 8];
  float scZ[20 * 8];
  float mHJ[8 * 8];
  float biasO8[8];
  float wsum8[8];
  float attA[8 * 9];
  float attZ[8 * 20];
  float oAcc[8 * 7];
  float peAcc8[8];
  int   Xa[SEQ];
  int   Xz[SEQ];
  float Xo[SEQ * 7];
};

// ---------- fused kernel: TWO batch elements per 512-thread block ----------
// bf16 weights: each 16B load covers 8 K-elements -> a burst of 4 loads covers
// 8 rows x 2 batches = 16 outputs (4x fewer loads, 2x fewer bytes than fp32).

__global__ __launch_bounds__(NT, 4) void nmstpp_fused(
    const int*   __restrict__ X,
    const float* __restrict__ emb_act,
    const float* __restrict__ emb_zone,
    const float* __restrict__ lin0_w,
    const float* __restrict__ lin0_b,
    const ushort* __restrict__ w16,       // bf16 weight image
    const float* __restrict__ qkv_b,
    const float* __restrict__ attn_o_b,
    const float* __restrict__ ln1_g, const float* __restrict__ ln1_b,
    const float* __restrict__ ff1_b,
    const float* __restrict__ ff2_b,
    const float* __restrict__ ln2_g, const float* __restrict__ ln2_b,
    const float* __restrict__ relu_b,
    const float* __restrict__ dT_b,
    const float* __restrict__ lindT_w,
    const float* __restrict__ lindT_b,
    const float* __restrict__ zn_b,
    const float* __restrict__ linzn_w,
    const float* __restrict__ linzn_b,
    const float* __restrict__ act0_b,
    const float* __restrict__ act1_b,
    const float* __restrict__ linact_w,
    const float* __restrict__ linact_b,
    float* __restrict__ out)
{
  const int tid   = threadIdx.x;
  const int wid   = tid >> 6;
  const int lane  = tid & 63;
  const int batch = tid >> 8;        // 0/1 for 256-split phases
  const int tp    = tid & 255;
  const int b     = 2 * blockIdx.x + batch;

  const ushort* qkv16  = w16 + OFF_QKV;
  const ushort* ao16   = w16 + OFF_AO;
  const ushort* ff116  = w16 + OFF_FF1;
  const ushort* ff216  = w16 + OFF_FF2;
  const ushort* relu16 = w16 + OFF_RELU;
  const ushort* dT16   = w16 + OFF_DT;
  const ushort* zn16   = w16 + OFF_ZN;
  const ushort* a016   = w16 + OFF_A0;
  const ushort* a116   = w16 + OFF_A1;

  __shared__ alignas(16) BatchBuf bb[2];
  __shared__ float embA[9 * 65];
  __shared__ float embZ[20 * 65];
  __shared__ float l0w[128 * 7];
  __shared__ float l0b[128];
  __shared__ float red[NW];

  BatchBuf* mb = &bb[batch];
  float* sc0 = bb[0].sc;
  float* sc1 = bb[1].sc;

  // ---- phase 0: stage tables + per-batch X / pe ----
  for (int i = tid; i < 9 * 64;  i += NT) embA[(i >> 6) * 65 + (i & 63)] = emb_act[i];
  for (int i = tid; i < 20 * 64; i += NT) embZ[(i >> 6) * 65 + (i & 63)] = emb_zone[i];
  for (int i = tid; i < 128 * 7; i += NT) l0w[i] = lin0_w[i];
  if (tid < 128) l0b[tid] = lin0_b[tid];
  {
    const int* xrow = X + (b * SEQ + tp) * 9;
    mb->Xa[tp] = xrow[0];
    mb->Xz[tp] = xrow[1];
    #pragma unroll
    for (int j = 0; j < 7; ++j) mb->Xo[tp * 7 + j] = (float)xrow[2 + j];
    float ex  = (float)(2 * tp) / (float)SEQ;
    float ang = (float)b * exp2f(-ex * 6.643856189774724f);  // 100^-ex
    mb->pe[tp] = ((tp & 1) == 0) ? sinf(ang) : cosf(ang);
  }
  __syncthreads();

  // ---- phase 1: src at last position ----
  {
    int av = mb->Xa[SEQ - 1], zv = mb->Xz[SEQ - 1];
    float v;
    if (tp < 64)        v = embA[av * 65 + tp];
    else if (tp < 128)  v = embZ[zv * 65 + (tp - 64)];
    else {
      const float* lr = l0w + (tp - 128) * 7;
      float acc = l0b[tp - 128];
      #pragma unroll
      for (int j = 0; j < 7; ++j) acc = fmaf(lr[j], mb->Xo[(SEQ - 1) * 7 + j], acc);
      v = acc;
    }
    mb->srcl[tp] = v + mb->pe[SEQ - 1];
  }
  __syncthreads();

  // ---- phase 2: q = Wq @ srcl + bq ----
  {
    X8 x0 = ldx8(bb[0].srcl, lane), x1 = ldx8(bb[1].srcl, lane);
    #pragma unroll
    for (int j = 0; j < 4; ++j) {
      int base = (wid + 8 * j) * 8;
      float p[8] = {};
      burst_acc(qkv16 + (size_t)base * 256, 256, lane, x0, x1, p);
      float u = fold8h(lane, p);
      int ro, bs;
      if (burst_writer(lane, ro, bs)) {
        int rr = base + ro;
        (bs ? bb[1].qv : bb[0].qv)[rr] = qkv_b[rr] + u;
      }
    }
  }
  __syncthreads();

  // ---- phase 3: w~[d][h] (bf16 column sweep; each load feeds both batches) ----
  {
    const float inv = 0.17677669529663687f;  // 1/sqrt(32)
    const int d = tid & 255;
    const int hbase = (tid < 256) ? 0 : 4;
    float acc[4][2] = {};
    for (int c = 0; c < 32; ++c) {
      #pragma unroll
      for (int hh = 0; hh < 4; ++hh) {
        int h = hbase + hh;
        float wv = bf2f(qkv16[(size_t)(DIM + h * 32 + c) * DIM + d]);
        acc[hh][0] = fmaf(bb[0].qv[h * 32 + c], wv, acc[hh][0]);
        acc[hh][1] = fmaf(bb[1].qv[h * 32 + c], wv, acc[hh][1]);
      }
    }
    #pragma unroll
    for (int hh = 0; hh < 4; ++hh) {
      bb[0].sc[d * 8 + hbase + hh] = acc[hh][0] * inv;
      bb[1].sc[d * 8 + hbase + hh] = acc[hh][1] * inv;
    }
  }
  __syncthreads();

  // ---- phase 3.5: collapse scores into lookup tables (312 slots x 2 batches) ----
  for (int s5 = tid; s5 < 624; s5 += NT) {
    int bt = (s5 >= 312);
    int t2 = s5 - 312 * bt;
    BatchBuf* mx = &bb[bt];
    if (t2 < 296) {
      int h = t2 / 37, k = t2 - h * 37;
      if (k < 9) {
        float acc = 0.f;
        for (int c = 0; c < 64; ++c) acc = fmaf(mx->sc[c * 8 + h], embA[k * 65 + c], acc);
        mx->scA[k * 8 + h] = acc;
      } else if (k < 29) {
        int z = k - 9; float acc = 0.f;
        for (int c = 0; c < 64; ++c) acc = fmaf(mx->sc[(64 + c) * 8 + h], embZ[z * 65 + c], acc);
        mx->scZ[z * 8 + h] = acc;
      } else if (k < 36) {
        int j = k - 29; float acc = 0.f;
        for (int kk = 0; kk < 128; ++kk) acc = fmaf(mx->sc[(128 + kk) * 8 + h], l0w[kk * 7 + j], acc);
        mx->mHJ[h * 8 + j] = acc;
      } else {
        float acc = 0.f;
        for (int c = 0; c < 256; ++c) acc += mx->sc[c * 8 + h];
        mx->wsum8[h] = acc;
      }
    } else if (t2 < 304) {
      int h = t2 - 296; float acc = 0.f;
      for (int kk = 0; kk < 128; ++kk) acc = fmaf(mx->sc[(128 + kk) * 8 + h], l0b[kk], acc);
      mx->biasO8[h] = acc;
    } else {
      int h = t2 - 304; float acc = 0.f;
      for (int c = 0; c < 32; ++c) acc += mx->qv[h * 32 + c] * qkv_b[DIM + h * 32 + c];
      mx->cb[h] = acc * 0.17677669529663687f;
    }
  }
  __syncthreads();

  // ---- phase 4: scores via tables (thread = (position, batch)) ----
  {
    const int sp = tp;
    int av = mb->Xa[sp], zv = mb->Xz[sp];
    float o[7];
    #pragma unroll
    for (int j = 0; j < 7; ++j) o[j] = mb->Xo[sp * 7 + j];
    float pes = mb->pe[sp];
    #pragma unroll
    for (int h = 0; h < NHEAD; ++h) {
      float acc = mb->scA[av * 8 + h] + mb->scZ[zv * 8 + h] + mb->biasO8[h] + mb->cb[h];
      acc = fmaf(pes, mb->wsum8[h], acc);
      #pragma unroll
      for (int j = 0; j < 7; ++j) acc = fmaf(mb->mHJ[h * 8 + j], o[j], acc);
      mb->sc[h * SEQ + sp] = acc;
    }
  }
  __syncthreads();

  // ---- phase 5: softmax per head, in-place transpose ----
  {
    float vals[8];
    int h = tp >> 5, idx = tp & 31;
    float m = -1e30f;
    #pragma unroll
    for (int i = 0; i < 8; ++i) {
      vals[i] = mb->sc[h * SEQ + idx * 8 + i];
      m = fmaxf(m, vals[i]);
    }
    #pragma unroll
    for (int off = 16; off > 0; off >>= 1) m = fmaxf(m, __shfl_xor(m, off, 32));
    float lsum = 0.f;
    #pragma unroll
    for (int i = 0; i < 8; ++i) { vals[i] = expf(vals[i] - m); lsum += vals[i]; }
    #pragma unroll
    for (int off = 16; off > 0; off >>= 1) lsum += __shfl_xor(lsum, off, 32);
    float rinv = 1.0f / lsum;
    __syncthreads();
    #pragma unroll
    for (int i = 0; i < 8; ++i) mb->sc[(idx * 8 + i) * 8 + h] = vals[i] * rinv;
  }
  __syncthreads();

  // ---- phase 6a: attention-weighted histograms / moments (296 x 2) ----
  for (int s6 = tid; s6 < 592; s6 += NT) {
    int bt = (s6 >= 296);
    int t2 = s6 - 296 * bt;
    BatchBuf* mx = &bb[bt];
    int h = t2 / 37, k = t2 - h * 37;
    float acc = 0.f;
    if (k < 29) {
      int mybin = (k < 9) ? k : (k - 9);
      const int* bins = (k < 9) ? mx->Xa : mx->Xz;
      for (int sp = 0; sp < SEQ; ++sp) {
        float at = mx->sc[sp * 8 + h];
        acc += (bins[sp] == mybin) ? at : 0.f;
      }
      if (k < 9) mx->attA[h * 9 + k] = acc; else mx->attZ[h * 20 + (k - 9)] = acc;
    } else if (k < 36) {
      int j = k - 29;
      for (int sp = 0; sp < SEQ; ++sp) acc = fmaf(mx->sc[sp * 8 + h], mx->Xo[sp * 7 + j], acc);
      mx->oAcc[h * 7 + j] = acc;
    } else {
      for (int sp = 0; sp < SEQ; ++sp) acc = fmaf(mx->sc[sp * 8 + h], mx->pe[sp], acc);
      mx->peAcc8[h] = acc;
    }
  }
  __syncthreads();

  // ---- phase 6b: reconstruct u[h][d] ----
  {
    float acc[NHEAD];
    #pragma unroll
    for (int h = 0; h < NHEAD; ++h) acc[h] = mb->peAcc8[h];
    if (tp < 64) {
      for (int a = 0; a < 9; ++a) {
        float ev = embA[a * 65 + tp];
        #pragma unroll
        for (int h = 0; h < NHEAD; ++h) acc[h] = fmaf(mb->attA[h * 9 + a], ev, acc[h]);
      }
    } else if (tp < 128) {
      int d2 = tp - 64;
      for (int z = 0; z < 20; ++z) {
        float ev = embZ[z * 65 + d2];
        #pragma unroll
        for (int h = 0; h < NHEAD; ++h) acc[h] = fmaf(mb->attZ[h * 20 + z], ev, acc[h]);
      }
    } else {
      int kk = tp - 128;
      #pragma unroll
      for (int j = 0; j < 7; ++j) {
        float ov = l0w[kk * 7 + j];
        #pragma unroll
        for (int h = 0; h < NHEAD; ++h) acc[h] = fmaf(mb->oAcc[h * 7 + j], ov, acc[h]);
      }
      #pragma unroll
      for (int h = 0; h < NHEAD; ++h) acc[h] += l0b[kk];
    }
    #pragma unroll
    for (int h = 0; h < NHEAD; ++h) mb->sc[h * DIM + tp] = acc[h];
  }
  __syncthreads();

  // ---- phase 7: ao = Wv @ u + bv (wave = head; rows wid*32..+31) ----
  {
    X8 x0 = ldx8(sc0 + wid * DIM, lane), x1 = ldx8(sc1 + wid * DIM, lane);
    #pragma unroll
    for (int j = 0; j < 4; ++j) {
      int base = wid * 32 + j * 8;
      float p[8] = {};
      burst_acc(qkv16 + (size_t)(2 * DIM + base) * 256, 256, lane, x0, x1, p);
      float u = fold8h(lane, p);
      int ro, bs;
      if (burst_writer(lane, ro, bs)) {
        int rr = base + ro;
        (bs ? bb[1].ao : bb[0].ao)[rr] = qkv_b[2 * DIM + rr] + u;
      }
    }
  }
  __syncthreads();

  // ---- phase 8: tv = srcl + attn_o(ao); h1 = LN1(tv) ----
  {
    X8 x0 = ldx8(bb[0].ao, lane), x1 = ldx8(bb[1].ao, lane);
    #pragma unroll
    for (int j = 0; j < 4; ++j) {
      int base = (wid + 8 * j) * 8;
      float p[8] = {};
      burst_acc(ao16 + (size_t)base * 256, 256, lane, x0, x1, p);
      float u = fold8h(lane, p);
      int ro, bs;
      if (burst_writer(lane, ro, bs)) {
        int rr = base + ro;
        BatchBuf* mx = &bb[bs];
        mx->qv[rr] = mx->srcl[rr] + attn_o_b[rr] + u;
      }
    }
  }
  __syncthreads();
  {
    float tv = mb->qv[tp];
    float mean = batch_sum(tv, red, wid, batch) * (1.0f / 256.0f);
    float dv = tv - mean;
    float var = batch_sum(dv * dv, red, wid, batch) * (1.0f / 256.0f);
    mb->h1[tp] = dv / sqrtf(var + 1e-5f) * ln1_g[tp] + ln1_b[tp];
  }
  __syncthreads();

  // ---- phase 9: ffb = relu(ff1 @ h1 + b) (1024 rows, 16 bursts/wave) ----
  {
    X8 x0 = ldx8(bb[0].h1, lane), x1 = ldx8(bb[1].h1, lane);
    for (int j = 0; j < 16; ++j) {
      int base = (wid + 8 * j) * 8;
      float p[8] = {};
      burst_acc(ff116 + (size_t)base * 256, 256, lane, x0, x1, p);
      float u = fold8h(lane, p);
      int ro, bs;
      if (burst_writer(lane, ro, bs)) {
        int rr = base + ro;
        (bs ? sc1 : sc0)[rr] = fmaxf(ff1_b[rr] + u, 0.f);
      }
    }
  }
  __syncthreads();

  // ---- phase 10: tv = h1 + ff2 @ ffb + b; h2 = LN2(tv) (K=1024, 4 chunks) ----
  {
    #pragma unroll
    for (int j = 0; j < 4; ++j) {
      int base = (wid + 8 * j) * 8;
      float p[8] = {};
      #pragma unroll
      for (int kc = 0; kc < 4; ++kc) {
        X8 x0 = ldx8(sc0 + kc * 256, lane), x1 = ldx8(sc1 + kc * 256, lane);
        burst_acc(ff216 + (size_t)base * 1024 + kc * 256, 1024, lane, x0, x1, p);
      }
      float u = fold8h(lane, p);
      int ro, bs;
      if (burst_writer(lane, ro, bs)) {
        int rr = base + ro;
        BatchBuf* mx = &bb[bs];
        mx->qv[rr] = mx->h1[rr] + ff2_b[rr] + u;
      }
    }
  }
  __syncthreads();
  {
    float tv = mb->qv[tp];
    float mean = batch_sum(tv, red, wid, batch) * (1.0f / 256.0f);
    float dv = tv - mean;
    float var = batch_sum(dv * dv, red, wid, batch) * (1.0f / 256.0f);
    mb->h2[tp] = dv / sqrtf(var + 1e-5f) * ln2_g[tp] + ln2_b[tp];
  }
  __syncthreads();

  // ---- phase 11: xr = relu_w @ h2 + b ----
  {
    X8 x0 = ldx8(bb[0].h2, lane), x1 = ldx8(bb[1].h2, lane);
    #pragma unroll
    for (int j = 0; j < 4; ++j) {
      int base = (wid + 8 * j) * 8;
      float p[8] = {};
      burst_acc(relu16 + (size_t)base * 256, 256, lane, x0, x1, p);
      float u = fold8h(lane, p);
      int ro, bs;
      if (burst_writer(lane, ro, bs)) {
        int rr = base + ro;
        (bs ? bb[1].xr : bb[0].xr)[rr] = relu_b[rr] + u;
      }
    }
  }
  __syncthreads();

  // ---- phase 12: d1 = dT_w @ xr + b; dT = lindT . d1 + b ----
  {
    X8 x0 = ldx8(bb[0].xr, lane), x1 = ldx8(bb[1].xr, lane);
    #pragma unroll
    for (int j = 0; j < 4; ++j) {
      int base = (wid + 8 * j) * 8;
      float p[8] = {};
      burst_acc(dT16 + (size_t)base * 256, 256, lane, x0, x1, p);
      float u = fold8h(lane, p);
      int ro, bs;
      if (burst_writer(lane, ro, bs)) {
        int rr = base + ro;
        (bs ? bb[1].h1 : bb[0].h1)[rr] = dT_b[rr] + u;     // h1 = d1
      }
    }
  }
  __syncthreads();
  float dTv;
  {
    float v = lindT_w[tp] * mb->h1[tp];
    dTv = batch_sum(v, red, wid, batch) + lindT_b[0];
  }

  // ---- phase 13: zn path (bf16 scalar, row pairs, fold4) ----
  mb->znin[1 + tp] = mb->xr[tp];
  mb->fa[21 + tp] = mb->xr[tp];
  if (tp == 0) { mb->znin[0] = dTv; mb->fa[20] = dTv; }
  __syncthreads();
  float* z1_0 = sc0 + 1024; float* z1_1 = sc1 + 1024;
  for (int r0 = 2 * wid; r0 < 257; r0 += 16) {
    int r1 = r0 + 1;
    bool has2 = (r1 < 257);
    const ushort* wa = zn16 + (size_t)r0 * 257;
    const ushort* wb = zn16 + (size_t)r1 * 257;
    float pa0 = 0.f, pa1 = 0.f, pb0 = 0.f, pb1 = 0.f;
    for (int j = lane; j < 257; j += 64) {
      float xa = bb[0].znin[j], xb = bb[1].znin[j];
      float w0 = bf2f(wa[j]);
      pa0 = fmaf(w0, xa, pa0); pa1 = fmaf(w0, xb, pa1);
      if (has2) { float w1 = bf2f(wb[j]); pb0 = fmaf(w1, xa, pb0); pb1 = fmaf(w1, xb, pb1); }
    }
    float u = fold4(lane, pa0, pa1, pb0, pb1);
    if ((lane & 15) == 0) {
      int g = lane >> 4;
      int rr = (g & 1) ? r1 : r0;             // g0:rA b0, g1:rB b0, g2:rA b1, g3:rB b1
      if (rr < 257) ((g & 2) ? z1_1 : z1_0)[rr] = zn_b[rr] + u;
    }
  }
  __syncthreads();
  for (int r0 = 2 * wid; r0 < 20; r0 += 16) {
    int r1 = r0 + 1;
    const float* wa = linzn_w + (size_t)r0 * 257;
    const float* wb = linzn_w + (size_t)r1 * 257;
    float pa0 = 0.f, pa1 = 0.f, pb0 = 0.f, pb1 = 0.f;
    for (int j = lane; j < 257; j += 64) {
      float x0v = z1_0[j], x1v = z1_1[j];
      float w0 = wa[j], w1 = wb[j];
      pa0 = fmaf(w0, x0v, pa0); pa1 = fmaf(w0, x1v, pa1);
      pb0 = fmaf(w1, x0v, pb0); pb1 = fmaf(w1, x1v, pb1);
    }
    float u = fold4(lane, pa0, pa1, pb0, pb1);
    if ((lane & 15) == 0) {
      int g = lane >> 4;
      int rr = (g & 1) ? r1 : r0;
      if (rr < 20) {
        BatchBuf* mx = &bb[(g >> 1)];
        float v = linzn_b[rr] + u;
        mx->znv[rr] = v; mx->fa[rr] = v;
      }
    }
  }
  __syncthreads();

  // ---- phase 14: ac = linact @ act1 @ act0 @ fa (bf16 scalar, fold4) ----
  float* a0_0 = sc0 + 1312; float* a0_1 = sc1 + 1312;
  for (int r0 = 2 * wid; r0 < 277; r0 += 16) {
    int r1 = r0 + 1;
    bool has2 = (r1 < 277);
    const ushort* wa = a016 + (size_t)r0 * 277;
    const ushort* wb = a016 + (size_t)r1 * 277;
    float pa0 = 0.f, pa1 = 0.f, pb0 = 0.f, pb1 = 0.f;
    for (int j = lane; j < 277; j += 64) {
      float xa = bb[0].fa[j], xb = bb[1].fa[j];
      float w0 = bf2f(wa[j]);
      pa0 = fmaf(w0, xa, pa0); pa1 = fmaf(w0, xb, pa1);
      if (has2) { float w1 = bf2f(wb[j]); pb0 = fmaf(w1, xa, pb0); pb1 = fmaf(w1, xb, pb1); }
    }
    float u = fold4(lane, pa0, pa1, pb0, pb1);
    if ((lane & 15) == 0) {
      int g = lane >> 4;
      int rr = (g & 1) ? r1 : r0;
      if (rr < 277) ((g & 2) ? a0_1 : a0_0)[rr] = act0_b[rr] + u;
    }
  }
  __syncthreads();
  float* a1_0 = sc0 + 1024; float* a1_1 = sc1 + 1024;  // z1 dead
  for (int r0 = 2 * wid; r0 < 277; r0 += 16) {
    int r1 = r0 + 1;
    bool has2 = (r1 < 277);
    const ushort* wa = a116 + (size_t)r0 * 277;
    const ushort* wb = a116 + (size_t)r1 * 277;
    float pa0 = 0.f, pa1 = 0.f, pb0 = 0.f, pb1 = 0.f;
    for (int j = lane; j < 277; j += 64) {
      float xa = a0_0[j], xb = a0_1[j];
      float w0 = bf2f(wa[j]);
      pa0 = fmaf(w0, xa, pa0); pa1 = fmaf(w0, xb, pa1);
      if (has2) { float w1 = bf2f(wb[j]); pb0 = fmaf(w1, xa, pb0); pb1 = fmaf(w1, xb, pb1); }
    }
    float u = fold4(lane, pa0, pa1, pb0, pb1);
    if ((lane & 15) == 0) {
      int g = lane >> 4;
      int rr = (g & 1) ? r1 : r0;
      if (rr < 277) ((g & 2) ? a1_1 : a1_0)[rr] = act1_b[rr] + u;
    }
  }
  __syncthreads();

  // ---- phase 15: outputs (fp32 small weights) ----
  for (int r = wid; r < 5; r += NW) {
    const float* wr = linact_w + (size_t)r * 277;
    float p0 = 0.f, p1 = 0.f;
    for (int j = lane; j < 277; j += 64) {
      float w = wr[j];
      p0 = fmaf(w, a1_0[j], p0);
      p1 = fmaf(w, a1_1[j], p1);
    }
    p0 = wave_allred(p0); p1 = wave_allred(p1);
    if (lane == 0) {
      out[(2 * blockIdx.x)     * 26 + 21 + r] = linact_b[r] + p0;
      out[(2 * blockIdx.x + 1) * 26 + 21 + r] = linact_b[r] + p1;
    }
  }
  if (tp == 0) out[b * 26] = dTv;
  if (tp < 20) out[b * 26 + 1 + tp] = mb->znv[tp];
}

// ---------- launcher ----------

extern "C" void kernel_launch(void* const* d_in, const int* in_sizes, int n_in,
                              void* d_out, int out_size, void* d_ws, size_t ws_size,
                              hipStream_t stream) {
  (void)in_sizes; (void)n_in; (void)out_size; (void)ws_size;
  const int*   X        = (const int*)  d_in[0];
  const float* emb_act  = (const float*)d_in[1];
  const float* emb_zone = (const float*)d_in[2];
  const float* lin0_w   = (const float*)d_in[3];
  const float* lin0_b   = (const float*)d_in[4];
  const float* qkv_w    = (const float*)d_in[5];
  const float* qkv_b    = (const float*)d_in[6];
  const float* attn_o_w = (const float*)d_in[7];
  const float* attn_o_b = (const float*)d_in[8];
  const float* ln1_g    = (const float*)d_in[9];
  const float* ln1_b    = (const float*)d_in[10];
  const float* ff1_w    = (const float*)d_in[11];
  const float* ff1_b    = (const float*)d_in[12];
  const float* ff2_w    = (const float*)d_in[13];
  const float* ff2_b    = (const float*)d_in[14];
  const float* ln2_g    = (const float*)d_in[15];
  const float* ln2_b    = (const float*)d_in[16];
  const float* relu_w   = (const float*)d_in[17];
  const float* relu_b   = (const float*)d_in[18];
  const float* dT_w     = (const float*)d_in[19];
  const float* dT_b     = (const float*)d_in[20];
  const float* lindT_w  = (const float*)d_in[21];
  const float* lindT_b  = (const float*)d_in[22];
  const float* zn_w     = (const float*)d_in[23];
  const float* zn_b     = (const float*)d_in[24];
  const float* linzn_w  = (const float*)d_in[25];
  const float* linzn_b  = (const float*)d_in[26];
  const float* act0_w   = (const float*)d_in[27];
  const float* act0_b   = (const float*)d_in[28];
  const float* act1_w   = (const float*)d_in[29];
  const float* act1_b   = (const float*)d_in[30];
  const float* linact_w = (const float*)d_in[31];
  const float* linact_b = (const float*)d_in[32];
  float* out = (float*)d_out;
  ushort* w16 = (ushort*)d_ws;   // needs 2.28 MB of workspace

  cvt_weights<<<dim3((CVT_TOTAL + 511) / 512), dim3(512), 0, stream>>>(
      qkv_w, attn_o_w, ff1_w, ff2_w, relu_w, dT_w, zn_w, act0_w, act1_w, w16);

  nmstpp_fused<<<dim3(BATCH / 2), dim3(NT), 0, stream>>>(
      X, emb_act, emb_zone, lin0_w, lin0_b, w16, qkv_b, attn_o_b,
      ln1_g, ln1_b, ff1_b, ff2_b, ln2_g, ln2_b,
      relu_b, dT_b, lindT_w, lindT_b, zn_b,
      linzn_w, linzn_b, act0_b, act1_b, linact_w, linact_b,
      out);
}

// Round 12
// 177.100 us; speedup vs baseline: 1.3259x; 1.0059x over previous
//
#include <hip/hip_runtime.h>
#include <math.h>

#define BATCH 512
#define SEQ   256
#define DIM   256
#define NHEAD 8
#define DFF   1024
#define NT    512   // threads per block
#define NW    8     // waves per block

typedef unsigned short ushort;
typedef unsigned int   uint;

// ---------- bf16 weight image layout in d_ws (ushort units) ----------
#define OFF_QKV   0u          // 768*256
#define OFF_AO    196608u     // 256*256
#define OFF_FF1   262144u     // 1024*256
#define OFF_FF2   524288u     // 256*1024
#define OFF_RELU  786432u     // 256*256
#define OFF_DT    851968u     // 256*256
#define OFF_ZN    917504u     // 257*257
#define OFF_A0    983553u     // 277*277
#define OFF_A1    1060282u    // 277*277
#define CVT_TOTAL 1137011u

// ---------- weight conversion kernel (runs every launch; deterministic) ----------
__global__ __launch_bounds__(512) void cvt_weights(
    const float* __restrict__ qkv, const float* __restrict__ ao,
    const float* __restrict__ ff1, const float* __restrict__ ff2,
    const float* __restrict__ relu, const float* __restrict__ dT,
    const float* __restrict__ zn, const float* __restrict__ a0,
    const float* __restrict__ a1, ushort* __restrict__ ws) {
  uint i = blockIdx.x * 512u + threadIdx.x;
  if (i >= CVT_TOTAL) return;
  const float* src; uint off;
  if      (i < OFF_AO)  { src = qkv;  off = OFF_QKV; }
  else if (i < OFF_FF1) { src = ao;   off = OFF_AO; }
  else if (i < OFF_FF2) { src = ff1;  off = OFF_FF1; }
  else if (i < OFF_RELU){ src = ff2;  off = OFF_FF2; }
  else if (i < OFF_DT)  { src = relu; off = OFF_RELU; }
  else if (i < OFF_ZN)  { src = dT;   off = OFF_DT; }
  else if (i < OFF_A0)  { src = zn;   off = OFF_ZN; }
  else if (i < OFF_A1)  { src = a0;   off = OFF_A0; }
  else                  { src = a1;   off = OFF_A1; }
  uint b = __float_as_uint(src[i - off]);
  uint r = (b + 0x7fffu + ((b >> 16) & 1u)) >> 16;   // round-to-nearest-even
  ws[i] = (ushort)r;
}

// ---------- helpers ----------

__device__ __forceinline__ float bf2f(ushort u) {
  return __uint_as_float(((uint)u) << 16);
}

__device__ __forceinline__ float wave_allred(float v) {
  #pragma unroll
  for (int off = 32; off > 0; off >>= 1) v += __shfl_xor(v, off, 64);
  return v;
}

// Reduce 4 independent partials over a full wave. 16-lane group g = lane>>4
// holds value [0,2,1,3][g].
__device__ __forceinline__ float fold4(int lane, float p0, float p1, float p2, float p3) {
  float za = (lane & 32) ? p1 : p0;
  float ta = (lane & 32) ? p0 : p1;
  za += __shfl_xor(ta, 32, 64);
  float zb = (lane & 32) ? p3 : p2;
  float tb = (lane & 32) ? p2 : p3;
  zb += __shfl_xor(tb, 32, 64);
  float u = (lane & 16) ? zb : za;
  float t = (lane & 16) ? za : zb;
  u += __shfl_xor(t, 16, 64);
  u += __shfl_xor(u, 8, 64);
  u += __shfl_xor(u, 4, 64);
  u += __shfl_xor(u, 2, 64);
  u += __shfl_xor(u, 1, 64);
  return u;
}

// Reduce 8 partials WITHIN each 32-lane half (9 shuffles).
// 4-lane group g=(lane>>2)&7 of each half holds value rev3(g).
__device__ __forceinline__ float fold8h(int lane, const float p[8]) {
  float z0 = (lane & 16) ? p[1] : p[0], y0 = (lane & 16) ? p[0] : p[1];
  z0 += __shfl_xor(y0, 16, 64);
  float z1 = (lane & 16) ? p[3] : p[2], y1 = (lane & 16) ? p[2] : p[3];
  z1 += __shfl_xor(y1, 16, 64);
  float z2 = (lane & 16) ? p[5] : p[4], y2 = (lane & 16) ? p[4] : p[5];
  z2 += __shfl_xor(y2, 16, 64);
  float z3 = (lane & 16) ? p[7] : p[6], y3 = (lane & 16) ? p[6] : p[7];
  z3 += __shfl_xor(y3, 16, 64);
  float w0 = (lane & 8) ? z1 : z0, s0 = (lane & 8) ? z0 : z1;
  w0 += __shfl_xor(s0, 8, 64);
  float w1 = (lane & 8) ? z3 : z2, s1 = (lane & 8) ? z2 : z3;
  w1 += __shfl_xor(s1, 8, 64);
  float u = (lane & 4) ? w1 : w0, t = (lane & 4) ? w0 : w1;
  u += __shfl_xor(t, 4, 64);
  u += __shfl_xor(u, 2, 64);
  u += __shfl_xor(u, 1, 64);
  return u;
}

// Writer lanes for a B=1 fold8h burst: (lane&3)==0; row = base + (lane>>5)*8 + rev3(g)
__device__ __forceinline__ bool burst_writer1(int lane, int& row_off) {
  if (lane & 3) return false;
  int g = (lane >> 2) & 7;
  int iv = ((g & 1) << 2) | (g & 2) | ((g >> 2) & 1);
  row_off = ((lane >> 5) << 3) + iv;
  return true;
}

struct X8 { float4 a, b; };

__device__ __forceinline__ X8 ldx8(const float* __restrict__ x, int lane) {
  int k = (lane & 31) * 8;
  X8 r;
  r.a = *(const float4*)(x + k);
  r.b = *(const float4*)(x + k + 4);
  return r;
}

__device__ __forceinline__ void accum1(uint4 w, const X8& x, float& p) {
  p = fmaf(__uint_as_float(w.x << 16),         x.a.x, p);
  p = fmaf(__uint_as_float(w.x & 0xffff0000u), x.a.y, p);
  p = fmaf(__uint_as_float(w.y << 16),         x.a.z, p);
  p = fmaf(__uint_as_float(w.y & 0xffff0000u), x.a.w, p);
  p = fmaf(__uint_as_float(w.z << 16),         x.b.x, p);
  p = fmaf(__uint_as_float(w.z & 0xffff0000u), x.b.y, p);
  p = fmaf(__uint_as_float(w.w << 16),         x.b.z, p);
  p = fmaf(__uint_as_float(w.w & 0xffff0000u), x.b.w, p);
}

// one burst: each 32-lane half covers 8 rows x K-slice of 256 (8 loads in flight)
__device__ __forceinline__ void burst_acc1(const ushort* __restrict__ Wb, int ld, int lane,
                                           const X8& x, float p[8]) {
  const ushort* wp = Wb + (size_t)((lane >> 5) * 8) * ld + (lane & 31) * 8;
  uint4 w0 = *(const uint4*)(wp);
  uint4 w1 = *(const uint4*)(wp + ld);
  uint4 w2 = *(const uint4*)(wp + 2 * ld);
  uint4 w3 = *(const uint4*)(wp + 3 * ld);
  uint4 w4 = *(const uint4*)(wp + 4 * ld);
  uint4 w5 = *(const uint4*)(wp + 5 * ld);
  uint4 w6 = *(const uint4*)(wp + 6 * ld);
  uint4 w7 = *(const uint4*)(wp + 7 * ld);
  accum1(w0, x, p[0]); accum1(w1, x, p[1]);
  accum1(w2, x, p[2]); accum1(w3, x, p[3]);
  accum1(w4, x, p[4]); accum1(w5, x, p[5]);
  accum1(w6, x, p[6]); accum1(w7, x, p[7]);
}

// block sum over 8 waves; ALL 512 threads must call
__device__ __forceinline__ float block_sum8(float v, float* red) {
  #pragma unroll
  for (int off = 32; off > 0; off >>= 1) v += __shfl_xor(v, off, 64);
  __syncthreads();
  if ((threadIdx.x & 63) == 0) red[threadIdx.x >> 6] = v;
  __syncthreads();
  float s = 0.f;
  #pragma unroll
  for (int i = 0; i < NW; ++i) s += red[i];
  return s;
}

struct Buf {
  float sc[2048];     // w~ [d][h] -> scores [h][s] -> att [s][h] -> u [h][d] -> ffb -> z1/a0/a1
  float pe[SEQ];
  float srcl[DIM];
  float qv[DIM];      // q -> tv(LN1) -> tv(LN2)
  float ao[DIM];
  float h1[DIM];      // h1 -> d1
  float h2[DIM];
  float xr[DIM];
  float znin[260];
  float fa[280];
  float znv[20];
  float cb[8];
  float scA[9 * 8];
  float scZ[20 * 8];
  float mHJ[8 * 8];
  float biasO8[8];
  float wsum8[8];
  float attA[8 * 9];
  float attZ[8 * 20];
  float oAcc[8 * 7];
  float peAcc8[8];
  int   Xa[SEQ];
  int   Xz[SEQ];
  float Xo[SEQ * 7];
};

// ---------- fused kernel: ONE batch element per 512-thread block ----------
// 512 blocks -> 2 blocks/CU (LDS ~41KB*2 <= 160KB). bf16 weight image (2.27MB)
// fits in each XCD's 4MB L2, so the B=1 re-reads are L2 hits (unlike round 10's
// fp32 4.5MB that spilled to L3). Burst: 8 loads in flight -> 16 rows/fold.

__global__ __launch_bounds__(NT, 4) void nmstpp_fused(
    const int*   __restrict__ X,
    const float* __restrict__ emb_act,
    const float* __restrict__ emb_zone,
    const float* __restrict__ lin0_w,
    const float* __restrict__ lin0_b,
    const ushort* __restrict__ w16,       // bf16 weight image
    const float* __restrict__ qkv_b,
    const float* __restrict__ attn_o_b,
    const float* __restrict__ ln1_g, const float* __restrict__ ln1_b,
    const float* __restrict__ ff1_b,
    const float* __restrict__ ff2_b,
    const float* __restrict__ ln2_g, const float* __restrict__ ln2_b,
    const float* __restrict__ relu_b,
    const float* __restrict__ dT_b,
    const float* __restrict__ lindT_w,
    const float* __restrict__ lindT_b,
    const float* __restrict__ zn_b,
    const float* __restrict__ linzn_w,
    const float* __restrict__ linzn_b,
    const float* __restrict__ act0_b,
    const float* __restrict__ act1_b,
    const float* __restrict__ linact_w,
    const float* __restrict__ linact_b,
    float* __restrict__ out)
{
  const int tid  = threadIdx.x;
  const int wid  = tid >> 6;          // 0..7
  const int lane = tid & 63;
  const int b    = blockIdx.x;
  const int hb4  = (tid >> 8) * 4;    // head-half: threads<256 -> heads 0-3, else 4-7
  const int dd   = tid & 255;         // channel/position for 256-wide split phases

  const ushort* qkv16  = w16 + OFF_QKV;
  const ushort* ao16   = w16 + OFF_AO;
  const ushort* ff116  = w16 + OFF_FF1;
  const ushort* ff216  = w16 + OFF_FF2;
  const ushort* relu16 = w16 + OFF_RELU;
  const ushort* dT16   = w16 + OFF_DT;
  const ushort* zn16   = w16 + OFF_ZN;
  const ushort* a016   = w16 + OFF_A0;
  const ushort* a116   = w16 + OFF_A1;

  __shared__ alignas(16) Buf s;
  __shared__ float embA[9 * 65];
  __shared__ float embZ[20 * 65];
  __shared__ float l0w[128 * 7];
  __shared__ float l0b[128];
  __shared__ float red[NW];

  // ---- phase 0: stage tables + X / pe ----
  for (int i = tid; i < 9 * 64;  i += NT) embA[(i >> 6) * 65 + (i & 63)] = emb_act[i];
  for (int i = tid; i < 20 * 64; i += NT) embZ[(i >> 6) * 65 + (i & 63)] = emb_zone[i];
  for (int i = tid; i < 128 * 7; i += NT) l0w[i] = lin0_w[i];
  if (tid < 128) l0b[tid] = lin0_b[tid];
  if (tid < SEQ) {
    const int* xrow = X + (b * SEQ + tid) * 9;
    s.Xa[tid] = xrow[0];
    s.Xz[tid] = xrow[1];
    #pragma unroll
    for (int j = 0; j < 7; ++j) s.Xo[tid * 7 + j] = (float)xrow[2 + j];
    float ex  = (float)(2 * tid) / (float)SEQ;
    float ang = (float)b * exp2f(-ex * 6.643856189774724f);  // 100^-ex
    s.pe[tid] = ((tid & 1) == 0) ? sinf(ang) : cosf(ang);
  }
  __syncthreads();

  // ---- phase 1: src at last position ----
  if (tid < DIM) {
    int av = s.Xa[SEQ - 1], zv = s.Xz[SEQ - 1];
    float v;
    if (tid < 64)        v = embA[av * 65 + tid];
    else if (tid < 128)  v = embZ[zv * 65 + (tid - 64)];
    else {
      const float* lr = l0w + (tid - 128) * 7;
      float acc = l0b[tid - 128];
      #pragma unroll
      for (int j = 0; j < 7; ++j) acc = fmaf(lr[j], s.Xo[(SEQ - 1) * 7 + j], acc);
      v = acc;
    }
    s.srcl[tid] = v + s.pe[SEQ - 1];
  }
  __syncthreads();

  // ---- phase 2: q = Wq @ srcl + bq (16 rows per wave-burst) ----
  {
    X8 x = ldx8(s.srcl, lane);
    #pragma unroll
    for (int j = 0; j < 2; ++j) {
      int base = (wid + 8 * j) * 16;
      float p[8] = {};
      burst_acc1(qkv16 + (size_t)base * 256, 256, lane, x, p);
      float u = fold8h(lane, p);
      int ro;
      if (burst_writer1(lane, ro)) {
        int rr = base + ro;
        s.qv[rr] = qkv_b[rr] + u;
      }
    }
  }
  __syncthreads();

  // ---- phase 3: w~[d][h] (bf16 column sweep; 4 heads per half) ----
  {
    const float inv = 0.17677669529663687f;  // 1/sqrt(32)
    float acc[4] = {};
    for (int c = 0; c < 32; ++c) {
      #pragma unroll
      for (int hh = 0; hh < 4; ++hh) {
        int h = hb4 + hh;
        float wv = bf2f(qkv16[(size_t)(DIM + h * 32 + c) * DIM + dd]);
        acc[hh] = fmaf(s.qv[h * 32 + c], wv, acc[hh]);
      }
    }
    #pragma unroll
    for (int hh = 0; hh < 4; ++hh) s.sc[dd * 8 + hb4 + hh] = acc[hh] * inv;
  }
  __syncthreads();

  // ---- phase 3.5: collapse scores into lookup tables ----
  if (tid < 312) {
    if (tid < 296) {
      int h = tid / 37, k = tid - h * 37;
      if (k < 9) {
        float acc = 0.f;
        for (int c = 0; c < 64; ++c) acc = fmaf(s.sc[c * 8 + h], embA[k * 65 + c], acc);
        s.scA[k * 8 + h] = acc;
      } else if (k < 29) {
        int z = k - 9; float acc = 0.f;
        for (int c = 0; c < 64; ++c) acc = fmaf(s.sc[(64 + c) * 8 + h], embZ[z * 65 + c], acc);
        s.scZ[z * 8 + h] = acc;
      } else if (k < 36) {
        int j = k - 29; float acc = 0.f;
        for (int kk = 0; kk < 128; ++kk) acc = fmaf(s.sc[(128 + kk) * 8 + h], l0w[kk * 7 + j], acc);
        s.mHJ[h * 8 + j] = acc;
      } else {
        float acc = 0.f;
        for (int c = 0; c < 256; ++c) acc += s.sc[c * 8 + h];
        s.wsum8[h] = acc;
      }
    } else if (tid < 304) {
      int h = tid - 296; float acc = 0.f;
      for (int kk = 0; kk < 128; ++kk) acc = fmaf(s.sc[(128 + kk) * 8 + h], l0b[kk], acc);
      s.biasO8[h] = acc;
    } else {
      int h = tid - 304; float acc = 0.f;
      for (int c = 0; c < 32; ++c) acc += s.qv[h * 32 + c] * qkv_b[DIM + h * 32 + c];
      s.cb[h] = acc * 0.17677669529663687f;
    }
  }
  __syncthreads();

  // ---- phase 4: scores via tables (thread = (position, head-half)) ----
  {
    const int sp = dd;
    int av = s.Xa[sp], zv = s.Xz[sp];
    float o[7];
    #pragma unroll
    for (int j = 0; j < 7; ++j) o[j] = s.Xo[sp * 7 + j];
    float pes = s.pe[sp];
    #pragma unroll
    for (int hh = 0; hh < 4; ++hh) {
      int h = hb4 + hh;
      float acc = s.scA[av * 8 + h] + s.scZ[zv * 8 + h] + s.biasO8[h] + s.cb[h];
      acc = fmaf(pes, s.wsum8[h], acc);
      #pragma unroll
      for (int j = 0; j < 7; ++j) acc = fmaf(s.mHJ[h * 8 + j], o[j], acc);
      s.sc[h * SEQ + sp] = acc;
    }
  }
  __syncthreads();

  // ---- phase 5: softmax, wave-per-head, in-place transpose ----
  {
    const int h = wid;
    float vals[4];
    float m = -1e30f;
    #pragma unroll
    for (int i = 0; i < 4; ++i) {
      vals[i] = s.sc[h * SEQ + lane * 4 + i];
      m = fmaxf(m, vals[i]);
    }
    #pragma unroll
    for (int off = 32; off > 0; off >>= 1) m = fmaxf(m, __shfl_xor(m, off, 64));
    float lsum = 0.f;
    #pragma unroll
    for (int i = 0; i < 4; ++i) { vals[i] = expf(vals[i] - m); lsum += vals[i]; }
    #pragma unroll
    for (int off = 32; off > 0; off >>= 1) lsum += __shfl_xor(lsum, off, 64);
    float rinv = 1.0f / lsum;
    __syncthreads();   // everyone done reading sc before transpose-overwrite
    #pragma unroll
    for (int i = 0; i < 4; ++i) s.sc[(lane * 4 + i) * 8 + h] = vals[i] * rinv;
  }
  __syncthreads();

  // ---- phase 6a: attention-weighted histograms / moments ----
  if (tid < 296) {
    int h = tid / 37, k = tid - h * 37;
    float acc = 0.f;
    if (k < 29) {
      int mybin = (k < 9) ? k : (k - 9);
      const int* bins = (k < 9) ? s.Xa : s.Xz;
      for (int sp = 0; sp < SEQ; ++sp) {
        float at = s.sc[sp * 8 + h];
        acc += (bins[sp] == mybin) ? at : 0.f;
      }
      if (k < 9) s.attA[h * 9 + k] = acc; else s.attZ[h * 20 + (k - 9)] = acc;
    } else if (k < 36) {
      int j = k - 29;
      for (int sp = 0; sp < SEQ; ++sp) acc = fmaf(s.sc[sp * 8 + h], s.Xo[sp * 7 + j], acc);
      s.oAcc[h * 7 + j] = acc;
    } else {
      for (int sp = 0; sp < SEQ; ++sp) acc = fmaf(s.sc[sp * 8 + h], s.pe[sp], acc);
      s.peAcc8[h] = acc;
    }
  }
  __syncthreads();

  // ---- phase 6b: reconstruct u[h][d] (4 heads per half) ----
  {
    float acc[4];
    #pragma unroll
    for (int hh = 0; hh < 4; ++hh) acc[hh] = s.peAcc8[hb4 + hh];
    if (dd < 64) {
      for (int a = 0; a < 9; ++a) {
        float ev = embA[a * 65 + dd];
        #pragma unroll
        for (int hh = 0; hh < 4; ++hh) acc[hh] = fmaf(s.attA[(hb4 + hh) * 9 + a], ev, acc[hh]);
      }
    } else if (dd < 128) {
      int d2 = dd - 64;
      for (int z = 0; z < 20; ++z) {
        float ev = embZ[z * 65 + d2];
        #pragma unroll
        for (int hh = 0; hh < 4; ++hh) acc[hh] = fmaf(s.attZ[(hb4 + hh) * 20 + z], ev, acc[hh]);
      }
    } else {
      int kk = dd - 128;
      #pragma unroll
      for (int j = 0; j < 7; ++j) {
        float ov = l0w[kk * 7 + j];
        #pragma unroll
        for (int hh = 0; hh < 4; ++hh) acc[hh] = fmaf(s.oAcc[(hb4 + hh) * 7 + j], ov, acc[hh]);
      }
      #pragma unroll
      for (int hh = 0; hh < 4; ++hh) acc[hh] += l0b[kk];
    }
    #pragma unroll
    for (int hh = 0; hh < 4; ++hh) s.sc[(hb4 + hh) * DIM + dd] = acc[hh];
  }
  __syncthreads();

  // ---- phase 7: ao = Wv @ u + bv (wave = head; rows wid*32..+31) ----
  {
    X8 x = ldx8(s.sc + wid * DIM, lane);
    #pragma unroll
    for (int j = 0; j < 2; ++j) {
      int base = wid * 32 + 16 * j;
      float p[8] = {};
      burst_acc1(qkv16 + (size_t)(2 * DIM + base) * 256, 256, lane, x, p);
      float u = fold8h(lane, p);
      int ro;
      if (burst_writer1(lane, ro)) {
        int rr = base + ro;
        s.ao[rr] = qkv_b[2 * DIM + rr] + u;
      }
    }
  }
  __syncthreads();

  // ---- phase 8: tv = srcl + attn_o(ao); h1 = LN1(tv) ----
  {
    X8 x = ldx8(s.ao, lane);
    #pragma unroll
    for (int j = 0; j < 2; ++j) {
      int base = (wid + 8 * j) * 16;
      float p[8] = {};
      burst_acc1(ao16 + (size_t)base * 256, 256, lane, x, p);
      float u = fold8h(lane, p);
      int ro;
      if (burst_writer1(lane, ro)) {
        int rr = base + ro;
        s.qv[rr] = s.srcl[rr] + attn_o_b[rr] + u;
      }
    }
  }
  __syncthreads();
  {
    float tv = (tid < DIM) ? s.qv[tid] : 0.f;
    float mean = block_sum8(tv, red) * (1.0f / 256.0f);
    float dv = (tid < DIM) ? (tv - mean) : 0.f;
    float var = block_sum8(dv * dv, red) * (1.0f / 256.0f);
    if (tid < DIM) s.h1[tid] = dv / sqrtf(var + 1e-5f) * ln1_g[tid] + ln1_b[tid];
  }
  __syncthreads();

  // ---- phase 9: ffb = relu(ff1 @ h1 + b) (1024 rows, 8 bursts/wave) ----
  {
    X8 x = ldx8(s.h1, lane);
    for (int j = 0; j < 8; ++j) {
      int base = (wid + 8 * j) * 16;
      float p[8] = {};
      burst_acc1(ff116 + (size_t)base * 256, 256, lane, x, p);
      float u = fold8h(lane, p);
      int ro;
      if (burst_writer1(lane, ro)) {
        int rr = base + ro;
        s.sc[rr] = fmaxf(ff1_b[rr] + u, 0.f);
      }
    }
  }
  __syncthreads();

  // ---- phase 10: tv = h1 + ff2 @ ffb + b; h2 = LN2(tv) (K=1024, 4 chunks) ----
  {
    #pragma unroll
    for (int j = 0; j < 2; ++j) {
      int base = (wid + 8 * j) * 16;
      float p[8] = {};
      #pragma unroll
      for (int kc = 0; kc < 4; ++kc) {
        X8 x = ldx8(s.sc + kc * 256, lane);
        burst_acc1(ff216 + (size_t)base * 1024 + kc * 256, 1024, lane, x, p);
      }
      float u = fold8h(lane, p);
      int ro;
      if (burst_writer1(lane, ro)) {
        int rr = base + ro;
        s.qv[rr] = s.h1[rr] + ff2_b[rr] + u;
      }
    }
  }
  __syncthreads();
  {
    float tv = (tid < DIM) ? s.qv[tid] : 0.f;
    float mean = block_sum8(tv, red) * (1.0f / 256.0f);
    float dv = (tid < DIM) ? (tv - mean) : 0.f;
    float var = block_sum8(dv * dv, red) * (1.0f / 256.0f);
    if (tid < DIM) s.h2[tid] = dv / sqrtf(var + 1e-5f) * ln2_g[tid] + ln2_b[tid];
  }
  __syncthreads();

  // ---- phase 11: xr = relu_w @ h2 + b ----
  {
    X8 x = ldx8(s.h2, lane);
    #pragma unroll
    for (int j = 0; j < 2; ++j) {
      int base = (wid + 8 * j) * 16;
      float p[8] = {};
      burst_acc1(relu16 + (size_t)base * 256, 256, lane, x, p);
      float u = fold8h(lane, p);
      int ro;
      if (burst_writer1(lane, ro)) {
        int rr = base + ro;
        s.xr[rr] = relu_b[rr] + u;
      }
    }
  }
  __syncthreads();

  // ---- phase 12: d1 = dT_w @ xr + b; dT = lindT . d1 + b ----
  {
    X8 x = ldx8(s.xr, lane);
    #pragma unroll
    for (int j = 0; j < 2; ++j) {
      int base = (wid + 8 * j) * 16;
      float p[8] = {};
      burst_acc1(dT16 + (size_t)base * 256, 256, lane, x, p);
      float u = fold8h(lane, p);
      int ro;
      if (burst_writer1(lane, ro)) {
        int rr = base + ro;
        s.h1[rr] = dT_b[rr] + u;             // h1 = d1
      }
    }
  }
  __syncthreads();
  float dTv;
  {
    float v = (tid < DIM) ? lindT_w[tid] * s.h1[tid] : 0.f;
    dTv = block_sum8(v, red) + lindT_b[0];
  }

  // ---- phase 13: zn path (bf16 scalar rows, fold4) ----
  if (tid < DIM) { s.znin[1 + tid] = s.xr[tid]; s.fa[21 + tid] = s.xr[tid]; }
  if (tid == 0)  { s.znin[0] = dTv; s.fa[20] = dTv; }
  __syncthreads();
  float* z1 = s.sc + 1024;   // 257 floats
  for (int r0 = 4 * wid; r0 < 257; r0 += 4 * NW) {
    int nrow = 257 - r0; if (nrow > 4) nrow = 4;
    float p0 = 0, p1 = 0, p2 = 0, p3 = 0;
    for (int j = lane; j < 257; j += 64) {
      float xv = s.znin[j];
      const ushort* wp = zn16 + (size_t)r0 * 257 + j;
      p0 = fmaf(bf2f(wp[0]), xv, p0);
      if (nrow > 1) p1 = fmaf(bf2f(wp[257]), xv, p1);
      if (nrow > 2) p2 = fmaf(bf2f(wp[2 * 257]), xv, p2);
      if (nrow > 3) p3 = fmaf(bf2f(wp[3 * 257]), xv, p3);
    }
    float u = fold4(lane, p0, p1, p2, p3);
    if ((lane & 15) == 0) {
      int g = lane >> 4;
      int rr = r0 + ((g & 1) << 1) + (g >> 1);
      if (rr < 257) z1[rr] = zn_b[rr] + u;
    }
  }
  __syncthreads();
  for (int r0 = 4 * wid; r0 < 20; r0 += 4 * NW) {
    float p0 = 0, p1 = 0, p2 = 0, p3 = 0;
    for (int j = lane; j < 257; j += 64) {
      float xv = z1[j];
      const float* wp = linzn_w + (size_t)r0 * 257 + j;
      p0 = fmaf(wp[0], xv, p0);
      p1 = fmaf(wp[257], xv, p1);
      p2 = fmaf(wp[2 * 257], xv, p2);
      p3 = fmaf(wp[3 * 257], xv, p3);
    }
    float u = fold4(lane, p0, p1, p2, p3);
    if ((lane & 15) == 0) {
      int g = lane >> 4;
      int rr = r0 + ((g & 1) << 1) + (g >> 1);
      if (rr < 20) { float v = linzn_b[rr] + u; s.znv[rr] = v; s.fa[rr] = v; }
    }
  }
  __syncthreads();

  // ---- phase 14: ac = linact @ act1 @ act0 @ fa (bf16 scalar, fold4) ----
  float* a0v = s.sc + 1312;  // 277 floats
  for (int r0 = 4 * wid; r0 < 277; r0 += 4 * NW) {
    int nrow = 277 - r0; if (nrow > 4) nrow = 4;
    float p0 = 0, p1 = 0, p2 = 0, p3 = 0;
    for (int j = lane; j < 277; j += 64) {
      float xv = s.fa[j];
      const ushort* wp = a016 + (size_t)r0 * 277 + j;
      p0 = fmaf(bf2f(wp[0]), xv, p0);
      if (nrow > 1) p1 = fmaf(bf2f(wp[277]), xv, p1);
      if (nrow > 2) p2 = fmaf(bf2f(wp[2 * 277]), xv, p2);
      if (nrow > 3) p3 = fmaf(bf2f(wp[3 * 277]), xv, p3);
    }
    float u = fold4(lane, p0, p1, p2, p3);
    if ((lane & 15) == 0) {
      int g = lane >> 4;
      int rr = r0 + ((g & 1) << 1) + (g >> 1);
      if (rr < 277) a0v[rr] = act0_b[rr] + u;
    }
  }
  __syncthreads();
  float* a1v = s.sc + 1024;  // z1 dead
  for (int r0 = 4 * wid; r0 < 277; r0 += 4 * NW) {
    int nrow = 277 - r0; if (nrow > 4) nrow = 4;
    float p0 = 0, p1 = 0, p2 = 0, p3 = 0;
    for (int j = lane; j < 277; j += 64) {
      float xv = a0v[j];
      const ushort* wp = a116 + (size_t)r0 * 277 + j;
      p0 = fmaf(bf2f(wp[0]), xv, p0);
      if (nrow > 1) p1 = fmaf(bf2f(wp[277]), xv, p1);
      if (nrow > 2) p2 = fmaf(bf2f(wp[2 * 277]), xv, p2);
      if (nrow > 3) p3 = fmaf(bf2f(wp[3 * 277]), xv, p3);
    }
    float u = fold4(lane, p0, p1, p2, p3);
    if ((lane & 15) == 0) {
      int g = lane >> 4;
      int rr = r0 + ((g & 1) << 1) + (g >> 1);
      if (rr < 277) a1v[rr] = act1_b[rr] + u;
    }
  }
  __syncthreads();

  // ---- phase 15: outputs ----
  if (wid < 5) {
    const float* wr = linact_w + (size_t)wid * 277;
    float p = 0.f;
    for (int j = lane; j < 277; j += 64) p = fmaf(wr[j], a1v[j], p);
    #pragma unroll
    for (int off = 32; off > 0; off >>= 1) p += __shfl_xor(p, off, 64);
    if (lane == 0) out[b * 26 + 21 + wid] = linact_b[wid] + p;
  }
  if (tid == 0) out[b * 26] = dTv;
  if (tid < 20) out[b * 26 + 1 + tid] = s.znv[tid];
}

// ---------- launcher ----------

extern "C" void kernel_launch(void* const* d_in, const int* in_sizes, int n_in,
                              void* d_out, int out_size, void* d_ws, size_t ws_size,
                              hipStream_t stream) {
  (void)in_sizes; (void)n_in; (void)out_size; (void)ws_size;
  const int*   X        = (const int*)  d_in[0];
  const float* emb_act  = (const float*)d_in[1];
  const float* emb_zone = (const float*)d_in[2];
  const float* lin0_w   = (const float*)d_in[3];
  const float* lin0_b   = (const float*)d_in[4];
  const float* qkv_w    = (const float*)d_in[5];
  const float* qkv_b    = (const float*)d_in[6];
  const float* attn_o_w = (const float*)d_in[7];
  const float* attn_o_b = (const float*)d_in[8];
  const float* ln1_g    = (const float*)d_in[9];
  const float* ln1_b    = (const float*)d_in[10];
  const float* ff1_w    = (const float*)d_in[11];
  const float* ff1_b    = (const float*)d_in[12];
  const float* ff2_w    = (const float*)d_in[13];
  const float* ff2_b    = (const float*)d_in[14];
  const float* ln2_g    = (const float*)d_in[15];
  const float* ln2_b    = (const float*)d_in[16];
  const float* relu_w   = (const float*)d_in[17];
  const float* relu_b   = (const float*)d_in[18];
  const float* dT_w     = (const float*)d_in[19];
  const float* dT_b     = (const float*)d_in[20];
  const float* lindT_w  = (const float*)d_in[21];
  const float* lindT_b  = (const float*)d_in[22];
  const float* zn_w     = (const float*)d_in[23];
  const float* zn_b     = (const float*)d_in[24];
  const float* linzn_w  = (const float*)d_in[25];
  const float* linzn_b  = (const float*)d_in[26];
  const float* act0_w   = (const float*)d_in[27];
  const float* act0_b   = (const float*)d_in[28];
  const float* act1_w   = (const float*)d_in[29];
  const float* act1_b   = (const float*)d_in[30];
  const float* linact_w = (const float*)d_in[31];
  const float* linact_b = (const float*)d_in[32];
  float* out = (float*)d_out;
  ushort* w16 = (ushort*)d_ws;   // needs 2.28 MB of workspace

  cvt_weights<<<dim3((CVT_TOTAL + 511) / 512), dim3(512), 0, stream>>>(
      qkv_w, attn_o_w, ff1_w, ff2_w, relu_w, dT_w, zn_w, act0_w, act1_w, w16);

  nmstpp_fused<<<dim3(BATCH), dim3(NT), 0, stream>>>(
      X, emb_act, emb_zone, lin0_w, lin0_b, w16, qkv_b, attn_o_b,
      ln1_g, ln1_b, ff1_b, ff2_b, ln2_g, ln2_b,
      relu_b, dT_b, lindT_w, lindT_b, zn_b,
      linzn_w, linzn_b, act0_b, act1_b, linact_w, linact_b,
      out);
}

// Round 14
// 171.020 us; speedup vs baseline: 1.3730x; 1.0356x over previous
//
#include <hip/hip_runtime.h>
#include <math.h>

#define BATCH 512
#define SEQ   256
#define DIM   256
#define NHEAD 8
#define DFF   1024
#define NT    512   // threads per block
#define NW    8     // waves per block

typedef unsigned short ushort;
typedef unsigned int   uint;
typedef __fp16 half2v __attribute__((ext_vector_type(2)));

// ---------- f16 weight image layout in d_ws (ushort units) ----------
#define OFF_QKV   0u          // 768*256
#define OFF_AO    196608u     // 256*256
#define OFF_FF1   262144u     // 1024*256
#define OFF_FF2   524288u     // 256*1024
#define OFF_RELU  786432u     // 256*256
#define OFF_DT    851968u     // 256*256
#define OFF_ZN    917504u     // 257*257
#define OFF_A0    983553u     // 277*277
#define OFF_A1    1060282u    // 277*277
#define CVT_TOTAL 1137011u

// ---------- weight conversion kernel (runs every launch; deterministic) ----------
__global__ __launch_bounds__(512) void cvt_weights(
    const float* __restrict__ qkv, const float* __restrict__ ao,
    const float* __restrict__ ff1, const float* __restrict__ ff2,
    const float* __restrict__ relu, const float* __restrict__ dT,
    const float* __restrict__ zn, const float* __restrict__ a0,
    const float* __restrict__ a1, ushort* __restrict__ ws) {
  uint i = blockIdx.x * 512u + threadIdx.x;
  if (i >= CVT_TOTAL) return;
  const float* src; uint off;
  if      (i < OFF_AO)  { src = qkv;  off = OFF_QKV; }
  else if (i < OFF_FF1) { src = ao;   off = OFF_AO; }
  else if (i < OFF_FF2) { src = ff1;  off = OFF_FF1; }
  else if (i < OFF_RELU){ src = ff2;  off = OFF_FF2; }
  else if (i < OFF_DT)  { src = relu; off = OFF_RELU; }
  else if (i < OFF_ZN)  { src = dT;   off = OFF_DT; }
  else if (i < OFF_A0)  { src = zn;   off = OFF_ZN; }
  else if (i < OFF_A1)  { src = a0;   off = OFF_A0; }
  else                  { src = a1;   off = OFF_A1; }
  __fp16 h = (__fp16)src[i - off];          // RNE
  union { __fp16 h; ushort u; } c; c.h = h;
  ws[i] = c.u;
}

// ---------- helpers ----------

__device__ __forceinline__ half2v u2h(uint u) {
  union { uint u; half2v h; } c; c.u = u; return c.h;
}

__device__ __forceinline__ float wave_allred(float v) {
  #pragma unroll
  for (int off = 32; off > 0; off >>= 1) v += __shfl_xor(v, off, 64);
  return v;
}

// Reduce 4 independent partials over a full wave. 16-lane group g = lane>>4
// holds value [0,2,1,3][g].
__device__ __forceinline__ float fold4(int lane, float p0, float p1, float p2, float p3) {
  float za = (lane & 32) ? p1 : p0;
  float ta = (lane & 32) ? p0 : p1;
  za += __shfl_xor(ta, 32, 64);
  float zb = (lane & 32) ? p3 : p2;
  float tb = (lane & 32) ? p2 : p3;
  zb += __shfl_xor(tb, 32, 64);
  float u = (lane & 16) ? zb : za;
  float t = (lane & 16) ? za : zb;
  u += __shfl_xor(t, 16, 64);
  u += __shfl_xor(u, 8, 64);
  u += __shfl_xor(u, 4, 64);
  u += __shfl_xor(u, 2, 64);
  u += __shfl_xor(u, 1, 64);
  return u;
}

// Reduce 8 partials WITHIN each 32-lane half (9 shuffles).
// 4-lane group g=(lane>>2)&7 of each half holds value rev3(g).
__device__ __forceinline__ float fold8h(int lane, const float p[8]) {
  float z0 = (lane & 16) ? p[1] : p[0], y0 = (lane & 16) ? p[0] : p[1];
  z0 += __shfl_xor(y0, 16, 64);
  float z1 = (lane & 16) ? p[3] : p[2], y1 = (lane & 16) ? p[2] : p[3];
  z1 += __shfl_xor(y1, 16, 64);
  float z2 = (lane & 16) ? p[5] : p[4], y2 = (lane & 16) ? p[4] : p[5];
  z2 += __shfl_xor(y2, 16, 64);
  float z3 = (lane & 16) ? p[7] : p[6], y3 = (lane & 16) ? p[6] : p[7];
  z3 += __shfl_xor(y3, 16, 64);
  float w0 = (lane & 8) ? z1 : z0, s0 = (lane & 8) ? z0 : z1;
  w0 += __shfl_xor(s0, 8, 64);
  float w1 = (lane & 8) ? z3 : z2, s1 = (lane & 8) ? z2 : z3;
  w1 += __shfl_xor(s1, 8, 64);
  float u = (lane & 4) ? w1 : w0, t = (lane & 4) ? w0 : w1;
  u += __shfl_xor(t, 4, 64);
  u += __shfl_xor(u, 2, 64);
  u += __shfl_xor(u, 1, 64);
  return u;
}

// Writer lanes for a B=1 fold8h burst: (lane&3)==0; row = base + (lane>>5)*8 + rev3(g)
__device__ __forceinline__ bool burst_writer1(int lane, int& row_off) {
  if (lane & 3) return false;
  int g = (lane >> 2) & 7;
  int iv = ((g & 1) << 2) | (g & 2) | ((g >> 2) & 1);
  row_off = ((lane >> 5) << 3) + iv;
  return true;
}

struct XH { half2v h[4]; };   // 8 f16 activations, 4 VGPRs

__device__ __forceinline__ XH ldx8h(const float* __restrict__ x, int lane) {
  int k = (lane & 31) * 8;
  XH r;
  r.h[0] = __builtin_amdgcn_cvt_pkrtz(x[k],     x[k + 1]);
  r.h[1] = __builtin_amdgcn_cvt_pkrtz(x[k + 2], x[k + 3]);
  r.h[2] = __builtin_amdgcn_cvt_pkrtz(x[k + 4], x[k + 5]);
  r.h[3] = __builtin_amdgcn_cvt_pkrtz(x[k + 6], x[k + 7]);
  return r;
}

// 8 f16 weights (uint4) . 8 f16 activations via 4x v_dot2_f32_f16
__device__ __forceinline__ void accum1(uint4 w, const XH& x, float& p) {
  p = __builtin_amdgcn_fdot2(u2h(w.x), x.h[0], p, false);
  p = __builtin_amdgcn_fdot2(u2h(w.y), x.h[1], p, false);
  p = __builtin_amdgcn_fdot2(u2h(w.z), x.h[2], p, false);
  p = __builtin_amdgcn_fdot2(u2h(w.w), x.h[3], p, false);
}

// one burst: each 32-lane half covers 8 rows x K-slice of 256 (8 loads in flight)
__device__ __forceinline__ void burst_acc1(const ushort* __restrict__ Wb, int ld, int lane,
                                           const XH& x, float p[8]) {
  const ushort* wp = Wb + (size_t)((lane >> 5) * 8) * ld + (lane & 31) * 8;
  uint4 w0 = *(const uint4*)(wp);
  uint4 w1 = *(const uint4*)(wp + ld);
  uint4 w2 = *(const uint4*)(wp + 2 * ld);
  uint4 w3 = *(const uint4*)(wp + 3 * ld);
  uint4 w4 = *(const uint4*)(wp + 4 * ld);
  uint4 w5 = *(const uint4*)(wp + 5 * ld);
  uint4 w6 = *(const uint4*)(wp + 6 * ld);
  uint4 w7 = *(const uint4*)(wp + 7 * ld);
  accum1(w0, x, p[0]); accum1(w1, x, p[1]);
  accum1(w2, x, p[2]); accum1(w3, x, p[3]);
  accum1(w4, x, p[4]); accum1(w5, x, p[5]);
  accum1(w6, x, p[6]); accum1(w7, x, p[7]);
}

// block sum over 8 waves; ALL 512 threads must call
__device__ __forceinline__ float block_sum8(float v, float* red) {
  #pragma unroll
  for (int off = 32; off > 0; off >>= 1) v += __shfl_xor(v, off, 64);
  __syncthreads();
  if ((threadIdx.x & 63) == 0) red[threadIdx.x >> 6] = v;
  __syncthreads();
  float s = 0.f;
  #pragma unroll
  for (int i = 0; i < NW; ++i) s += red[i];
  return s;
}

struct Buf {
  float sc[2048];     // w~ [d][h] -> scores [h][s] -> att [s][h] -> u [h][d] -> ffb -> z1/a0/a1
  float pe[SEQ];
  float srcl[DIM];
  float qv[DIM];      // q -> tv(LN1) -> tv(LN2)
  float ao[DIM];
  float h1[DIM];      // h1 -> d1
  float h2[DIM];
  float xr[DIM];
  float znin[260];
  float fa[280];
  float znv[20];
  float cb[8];
  float scA[9 * 8];
  float scZ[20 * 8];
  float mHJ[8 * 8];
  float biasO8[8];
  float wsum8[8];
  float attA[8 * 9];
  float attZ[8 * 20];
  float oAcc[8 * 7];
  float peAcc8[8];
  int   Xa[SEQ];
  int   Xz[SEQ];
  float Xo[SEQ * 7];
};

// ---------- fused kernel: ONE batch element per 512-thread block ----------
// 512 blocks -> 2 blocks/CU. f16 weight image (2.27MB) is L2-resident.
// GEMV burst: 8 uint4 loads -> 32 v_dot2_f32_f16 (4x less VALU than bf16 unpack).

__global__ __launch_bounds__(NT, 4) void nmstpp_fused(
    const int*   __restrict__ X,
    const float* __restrict__ emb_act,
    const float* __restrict__ emb_zone,
    const float* __restrict__ lin0_w,
    const float* __restrict__ lin0_b,
    const ushort* __restrict__ w16,       // f16 weight image
    const float* __restrict__ qkv_b,
    const float* __restrict__ attn_o_b,
    const float* __restrict__ ln1_g, const float* __restrict__ ln1_b,
    const float* __restrict__ ff1_b,
    const float* __restrict__ ff2_b,
    const float* __restrict__ ln2_g, const float* __restrict__ ln2_b,
    const float* __restrict__ relu_b,
    const float* __restrict__ dT_b,
    const float* __restrict__ lindT_w,
    const float* __restrict__ lindT_b,
    const float* __restrict__ zn_b,
    const float* __restrict__ linzn_w,
    const float* __restrict__ linzn_b,
    const float* __restrict__ act0_b,
    const float* __restrict__ act1_b,
    const float* __restrict__ linact_w,
    const float* __restrict__ linact_b,
    float* __restrict__ out)
{
  const int tid  = threadIdx.x;
  const int wid  = tid >> 6;          // 0..7
  const int lane = tid & 63;
  const int b    = blockIdx.x;
  const int hb4  = (tid >> 8) * 4;    // head-half: threads<256 -> heads 0-3, else 4-7
  const int dd   = tid & 255;         // channel/position for 256-wide split phases

  const ushort* qkv16  = w16 + OFF_QKV;
  const ushort* ao16   = w16 + OFF_AO;
  const ushort* ff116  = w16 + OFF_FF1;
  const ushort* ff216  = w16 + OFF_FF2;
  const ushort* relu16 = w16 + OFF_RELU;
  const ushort* dT16   = w16 + OFF_DT;
  const __fp16* qkvh = (const __fp16*)(w16 + OFF_QKV);
  const __fp16* znh  = (const __fp16*)(w16 + OFF_ZN);
  const __fp16* a0h  = (const __fp16*)(w16 + OFF_A0);
  const __fp16* a1h  = (const __fp16*)(w16 + OFF_A1);

  __shared__ alignas(16) Buf s;
  __shared__ float embA[9 * 65];
  __shared__ float embZ[20 * 65];
  __shared__ float l0w[128 * 7];
  __shared__ float l0b[128];
  __shared__ float red[NW];

  // ---- phase 0: stage tables + X / pe ----
  for (int i = tid; i < 9 * 64;  i += NT) embA[(i >> 6) * 65 + (i & 63)] = emb_act[i];
  for (int i = tid; i < 20 * 64; i += NT) embZ[(i >> 6) * 65 + (i & 63)] = emb_zone[i];
  for (int i = tid; i < 128 * 7; i += NT) l0w[i] = lin0_w[i];
  if (tid < 128) l0b[tid] = lin0_b[tid];
  if (tid < SEQ) {
    const int* xrow = X + (b * SEQ + tid) * 9;
    s.Xa[tid] = xrow[0];
    s.Xz[tid] = xrow[1];
    #pragma unroll
    for (int j = 0; j < 7; ++j) s.Xo[tid * 7 + j] = (float)xrow[2 + j];
    float ex  = (float)(2 * tid) / (float)SEQ;
    float ang = (float)b * exp2f(-ex * 6.643856189774724f);  // 100^-ex
    s.pe[tid] = ((tid & 1) == 0) ? sinf(ang) : cosf(ang);
  }
  __syncthreads();

  // ---- phase 1: src at last position ----
  if (tid < DIM) {
    int av = s.Xa[SEQ - 1], zv = s.Xz[SEQ - 1];
    float v;
    if (tid < 64)        v = embA[av * 65 + tid];
    else if (tid < 128)  v = embZ[zv * 65 + (tid - 64)];
    else {
      const float* lr = l0w + (tid - 128) * 7;
      float acc = l0b[tid - 128];
      #pragma unroll
      for (int j = 0; j < 7; ++j) acc = fmaf(lr[j], s.Xo[(SEQ - 1) * 7 + j], acc);
      v = acc;
    }
    s.srcl[tid] = v + s.pe[SEQ - 1];
  }
  __syncthreads();

  // ---- phase 2: q = Wq @ srcl + bq (16 rows per wave-burst) ----
  {
    XH x = ldx8h(s.srcl, lane);
    #pragma unroll
    for (int j = 0; j < 2; ++j) {
      int base = (wid + 8 * j) * 16;
      float p[8] = {};
      burst_acc1(qkv16 + (size_t)base * 256, 256, lane, x, p);
      float u = fold8h(lane, p);
      int ro;
      if (burst_writer1(lane, ro)) {
        int rr = base + ro;
        s.qv[rr] = qkv_b[rr] + u;
      }
    }
  }
  __syncthreads();

  // ---- phase 3: w~[d][h] (f16 column sweep; 4 heads per half) ----
  {
    const float inv = 0.17677669529663687f;  // 1/sqrt(32)
    float acc[4] = {};
    for (int c = 0; c < 32; ++c) {
      #pragma unroll
      for (int hh = 0; hh < 4; ++hh) {
        int h = hb4 + hh;
        float wv = (float)qkvh[(size_t)(DIM + h * 32 + c) * DIM + dd];
        acc[hh] = fmaf(s.qv[h * 32 + c], wv, acc[hh]);
      }
    }
    #pragma unroll
    for (int hh = 0; hh < 4; ++hh) s.sc[dd * 8 + hb4 + hh] = acc[hh] * inv;
  }
  __syncthreads();

  // ---- phase 3.5: collapse scores into lookup tables ----
  if (tid < 312) {
    if (tid < 296) {
      int h = tid / 37, k = tid - h * 37;
      if (k < 9) {
        float acc = 0.f;
        for (int c = 0; c < 64; ++c) acc = fmaf(s.sc[c * 8 + h], embA[k * 65 + c], acc);
        s.scA[k * 8 + h] = acc;
      } else if (k < 29) {
        int z = k - 9; float acc = 0.f;
        for (int c = 0; c < 64; ++c) acc = fmaf(s.sc[(64 + c) * 8 + h], embZ[z * 65 + c], acc);
        s.scZ[z * 8 + h] = acc;
      } else if (k < 36) {
        int j = k - 29; float acc = 0.f;
        for (int kk = 0; kk < 128; ++kk) acc = fmaf(s.sc[(128 + kk) * 8 + h], l0w[kk * 7 + j], acc);
        s.mHJ[h * 8 + j] = acc;
      } else {
        float acc = 0.f;
        for (int c = 0; c < 256; ++c) acc += s.sc[c * 8 + h];
        s.wsum8[h] = acc;
      }
    } else if (tid < 304) {
      int h = tid - 296; float acc = 0.f;
      for (int kk = 0; kk < 128; ++kk) acc = fmaf(s.sc[(128 + kk) * 8 + h], l0b[kk], acc);
      s.biasO8[h] = acc;
    } else {
      int h = tid - 304; float acc = 0.f;
      for (int c = 0; c < 32; ++c) acc += s.qv[h * 32 + c] * qkv_b[DIM + h * 32 + c];
      s.cb[h] = acc * 0.17677669529663687f;
    }
  }
  __syncthreads();

  // ---- phase 4: scores via tables (thread = (position, head-half)) ----
  {
    const int sp = dd;
    int av = s.Xa[sp], zv = s.Xz[sp];
    float o[7];
    #pragma unroll
    for (int j = 0; j < 7; ++j) o[j] = s.Xo[sp * 7 + j];
    float pes = s.pe[sp];
    #pragma unroll
    for (int hh = 0; hh < 4; ++hh) {
      int h = hb4 + hh;
      float acc = s.scA[av * 8 + h] + s.scZ[zv * 8 + h] + s.biasO8[h] + s.cb[h];
      acc = fmaf(pes, s.wsum8[h], acc);
      #pragma unroll
      for (int j = 0; j < 7; ++j) acc = fmaf(s.mHJ[h * 8 + j], o[j], acc);
      s.sc[h * SEQ + sp] = acc;
    }
  }
  __syncthreads();

  // ---- phase 5: softmax, wave-per-head, in-place transpose ----
  {
    const int h = wid;
    float vals[4];
    float m = -1e30f;
    #pragma unroll
    for (int i = 0; i < 4; ++i) {
      vals[i] = s.sc[h * SEQ + lane * 4 + i];
      m = fmaxf(m, vals[i]);
    }
    #pragma unroll
    for (int off = 32; off > 0; off >>= 1) m = fmaxf(m, __shfl_xor(m, off, 64));
    float lsum = 0.f;
    #pragma unroll
    for (int i = 0; i < 4; ++i) { vals[i] = expf(vals[i] - m); lsum += vals[i]; }
    #pragma unroll
    for (int off = 32; off > 0; off >>= 1) lsum += __shfl_xor(lsum, off, 64);
    float rinv = 1.0f / lsum;
    __syncthreads();   // everyone done reading sc before transpose-overwrite
    #pragma unroll
    for (int i = 0; i < 4; ++i) s.sc[(lane * 4 + i) * 8 + h] = vals[i] * rinv;
  }
  __syncthreads();

  // ---- phase 6a: attention-weighted histograms / moments ----
  if (tid < 296) {
    int h = tid / 37, k = tid - h * 37;
    float acc = 0.f;
    if (k < 29) {
      int mybin = (k < 9) ? k : (k - 9);
      const int* bins = (k < 9) ? s.Xa : s.Xz;
      for (int sp = 0; sp < SEQ; ++sp) {
        float at = s.sc[sp * 8 + h];
        acc += (bins[sp] == mybin) ? at : 0.f;
      }
      if (k < 9) s.attA[h * 9 + k] = acc; else s.attZ[h * 20 + (k - 9)] = acc;
    } else if (k < 36) {
      int j = k - 29;
      for (int sp = 0; sp < SEQ; ++sp) acc = fmaf(s.sc[sp * 8 + h], s.Xo[sp * 7 + j], acc);
      s.oAcc[h * 7 + j] = acc;
    } else {
      for (int sp = 0; sp < SEQ; ++sp) acc = fmaf(s.sc[sp * 8 + h], s.pe[sp], acc);
      s.peAcc8[h] = acc;
    }
  }
  __syncthreads();

  // ---- phase 6b: reconstruct u[h][d] (4 heads per half) ----
  {
    float acc[4];
    #pragma unroll
    for (int hh = 0; hh < 4; ++hh) acc[hh] = s.peAcc8[hb4 + hh];
    if (dd < 64) {
      for (int a = 0; a < 9; ++a) {
        float ev = embA[a * 65 + dd];
        #pragma unroll
        for (int hh = 0; hh < 4; ++hh) acc[hh] = fmaf(s.attA[(hb4 + hh) * 9 + a], ev, acc[hh]);
      }
    } else if (dd < 128) {
      int d2 = dd - 64;
      for (int z = 0; z < 20; ++z) {
        float ev = embZ[z * 65 + d2];
        #pragma unroll
        for (int hh = 0; hh < 4; ++hh) acc[hh] = fmaf(s.attZ[(hb4 + hh) * 20 + z], ev, acc[hh]);
      }
    } else {
      int kk = dd - 128;
      #pragma unroll
      for (int j = 0; j < 7; ++j) {
        float ov = l0w[kk * 7 + j];
        #pragma unroll
        for (int hh = 0; hh < 4; ++hh) acc[hh] = fmaf(s.oAcc[(hb4 + hh) * 7 + j], ov, acc[hh]);
      }
      #pragma unroll
      for (int hh = 0; hh < 4; ++hh) acc[hh] += l0b[kk];
    }
    #pragma unroll
    for (int hh = 0; hh < 4; ++hh) s.sc[(hb4 + hh) * DIM + dd] = acc[hh];
  }
  __syncthreads();

  // ---- phase 7: ao = Wv @ u + bv (wave = head; rows wid*32..+31) ----
  {
    XH x = ldx8h(s.sc + wid * DIM, lane);
    #pragma unroll
    for (int j = 0; j < 2; ++j) {
      int base = wid * 32 + 16 * j;
      float p[8] = {};
      burst_acc1(qkv16 + (size_t)(2 * DIM + base) * 256, 256, lane, x, p);
      float u = fold8h(lane, p);
      int ro;
      if (burst_writer1(lane, ro)) {
        int rr = base + ro;
        s.ao[rr] = qkv_b[2 * DIM + rr] + u;
      }
    }
  }
  __syncthreads();

  // ---- phase 8: tv = srcl + attn_o(ao); h1 = LN1(tv) ----
  {
    XH x = ldx8h(s.ao, lane);
    #pragma unroll
    for (int j = 0; j < 2; ++j) {
      int base = (wid + 8 * j) * 16;
      float p[8] = {};
      burst_acc1(ao16 + (size_t)base * 256, 256, lane, x, p);
      float u = fold8h(lane, p);
      int ro;
      if (burst_writer1(lane, ro)) {
        int rr = base + ro;
        s.qv[rr] = s.srcl[rr] + attn_o_b[rr] + u;
      }
    }
  }
  __syncthreads();
  {
    float tv = (tid < DIM) ? s.qv[tid] : 0.f;
    float mean = block_sum8(tv, red) * (1.0f / 256.0f);
    float dv = (tid < DIM) ? (tv - mean) : 0.f;
    float var = block_sum8(dv * dv, red) * (1.0f / 256.0f);
    if (tid < DIM) s.h1[tid] = dv / sqrtf(var + 1e-5f) * ln1_g[tid] + ln1_b[tid];
  }
  __syncthreads();

  // ---- phase 9: ffb = relu(ff1 @ h1 + b) (1024 rows, 8 bursts/wave) ----
  {
    XH x = ldx8h(s.h1, lane);
    for (int j = 0; j < 8; ++j) {
      int base = (wid + 8 * j) * 16;
      float p[8] = {};
      burst_acc1(ff116 + (size_t)base * 256, 256, lane, x, p);
      float u = fold8h(lane, p);
      int ro;
      if (burst_writer1(lane, ro)) {
        int rr = base + ro;
        s.sc[rr] = fmaxf(ff1_b[rr] + u, 0.f);
      }
    }
  }
  __syncthreads();

  // ---- phase 10: tv = h1 + ff2 @ ffb + b; h2 = LN2(tv) (K=1024, 4 chunks) ----
  {
    #pragma unroll
    for (int j = 0; j < 2; ++j) {
      int base = (wid + 8 * j) * 16;
      float p[8] = {};
      #pragma unroll
      for (int kc = 0; kc < 4; ++kc) {
        XH x = ldx8h(s.sc + kc * 256, lane);
        burst_acc1(ff216 + (size_t)base * 1024 + kc * 256, 1024, lane, x, p);
      }
      float u = fold8h(lane, p);
      int ro;
      if (burst_writer1(lane, ro)) {
        int rr = base + ro;
        s.qv[rr] = s.h1[rr] + ff2_b[rr] + u;
      }
    }
  }
  __syncthreads();
  {
    float tv = (tid < DIM) ? s.qv[tid] : 0.f;
    float mean = block_sum8(tv, red) * (1.0f / 256.0f);
    float dv = (tid < DIM) ? (tv - mean) : 0.f;
    float var = block_sum8(dv * dv, red) * (1.0f / 256.0f);
    if (tid < DIM) s.h2[tid] = dv / sqrtf(var + 1e-5f) * ln2_g[tid] + ln2_b[tid];
  }
  __syncthreads();

  // ---- phase 11: xr = relu_w @ h2 + b ----
  {
    XH x = ldx8h(s.h2, lane);
    #pragma unroll
    for (int j = 0; j < 2; ++j) {
      int base = (wid + 8 * j) * 16;
      float p[8] = {};
      burst_acc1(relu16 + (size_t)base * 256, 256, lane, x, p);
      float u = fold8h(lane, p);
      int ro;
      if (burst_writer1(lane, ro)) {
        int rr = base + ro;
        s.xr[rr] = relu_b[rr] + u;
      }
    }
  }
  __syncthreads();

  // ---- phase 12: d1 = dT_w @ xr + b; dT = lindT . d1 + b ----
  {
    XH x = ldx8h(s.xr, lane);
    #pragma unroll
    for (int j = 0; j < 2; ++j) {
      int base = (wid + 8 * j) * 16;
      float p[8] = {};
      burst_acc1(dT16 + (size_t)base * 256, 256, lane, x, p);
      float u = fold8h(lane, p);
      int ro;
      if (burst_writer1(lane, ro)) {
        int rr = base + ro;
        s.h1[rr] = dT_b[rr] + u;             // h1 = d1
      }
    }
  }
  __syncthreads();
  float dTv;
  {
    float v = (tid < DIM) ? lindT_w[tid] * s.h1[tid] : 0.f;
    dTv = block_sum8(v, red) + lindT_b[0];
  }

  // ---- phase 13: zn path (f16 scalar rows, fold4) ----
  if (tid < DIM) { s.znin[1 + tid] = s.xr[tid]; s.fa[21 + tid] = s.xr[tid]; }
  if (tid == 0)  { s.znin[0] = dTv; s.fa[20] = dTv; }
  __syncthreads();
  float* z1 = s.sc + 1024;   // 257 floats
  for (int r0 = 4 * wid; r0 < 257; r0 += 4 * NW) {
    int nrow = 257 - r0; if (nrow > 4) nrow = 4;
    float p0 = 0, p1 = 0, p2 = 0, p3 = 0;
    for (int j = lane; j < 257; j += 64) {
      float xv = s.znin[j];
      const __fp16* wp = znh + (size_t)r0 * 257 + j;
      p0 = fmaf((float)wp[0], xv, p0);
      if (nrow > 1) p1 = fmaf((float)wp[257], xv, p1);
      if (nrow > 2) p2 = fmaf((float)wp[2 * 257], xv, p2);
      if (nrow > 3) p3 = fmaf((float)wp[3 * 257], xv, p3);
    }
    float u = fold4(lane, p0, p1, p2, p3);
    if ((lane & 15) == 0) {
      int g = lane >> 4;
      int rr = r0 + ((g & 1) << 1) + (g >> 1);
      if (rr < 257) z1[rr] = zn_b[rr] + u;
    }
  }
  __syncthreads();
  for (int r0 = 4 * wid; r0 < 20; r0 += 4 * NW) {
    float p0 = 0, p1 = 0, p2 = 0, p3 = 0;
    for (int j = lane; j < 257; j += 64) {
      float xv = z1[j];
      const float* wp = linzn_w + (size_t)r0 * 257 + j;
      p0 = fmaf(wp[0], xv, p0);
      p1 = fmaf(wp[257], xv, p1);
      p2 = fmaf(wp[2 * 257], xv, p2);
      p3 = fmaf(wp[3 * 257], xv, p3);
    }
    float u = fold4(lane, p0, p1, p2, p3);
    if ((lane & 15) == 0) {
      int g = lane >> 4;
      int rr = r0 + ((g & 1) << 1) + (g >> 1);
      if (rr < 20) { float v = linzn_b[rr] + u; s.znv[rr] = v; s.fa[rr] = v; }
    }
  }
  __syncthreads();

  // ---- phase 14: ac = linact @ act1 @ act0 @ fa (f16 scalar, fold4) ----
  float* a0v = s.sc + 1312;  // 277 floats
  for (int r0 = 4 * wid; r0 < 277; r0 += 4 * NW) {
    int nrow = 277 - r0; if (nrow > 4) nrow = 4;
    float p0 = 0, p1 = 0, p2 = 0, p3 = 0;
    for (int j = lane; j < 277; j += 64) {
      float xv = s.fa[j];
      const __fp16* wp = a0h + (size_t)r0 * 277 + j;
      p0 = fmaf((float)wp[0], xv, p0);
      if (nrow > 1) p1 = fmaf((float)wp[277], xv, p1);
      if (nrow > 2) p2 = fmaf((float)wp[2 * 277], xv, p2);
      if (nrow > 3) p3 = fmaf((float)wp[3 * 277], xv, p3);
    }
    float u = fold4(lane, p0, p1, p2, p3);
    if ((lane & 15) == 0) {
      int g = lane >> 4;
      int rr = r0 + ((g & 1) << 1) + (g >> 1);
      if (rr < 277) a0v[rr] = act0_b[rr] + u;
    }
  }
  __syncthreads();
  float* a1v = s.sc + 1024;  // z1 dead
  for (int r0 = 4 * wid; r0 < 277; r0 += 4 * NW) {
    int nrow = 277 - r0; if (nrow > 4) nrow = 4;
    float p0 = 0, p1 = 0, p2 = 0, p3 = 0;
    for (int j = lane; j < 277; j += 64) {
      float xv = a0v[j];
      const __fp16* wp = a1h + (size_t)r0 * 277 + j;
      p0 = fmaf((float)wp[0], xv, p0);
      if (nrow > 1) p1 = fmaf((float)wp[277], xv, p1);
      if (nrow > 2) p2 = fmaf((float)wp[2 * 277], xv, p2);
      if (nrow > 3) p3 = fmaf((float)wp[3 * 277], xv, p3);
    }
    float u = fold4(lane, p0, p1, p2, p3);
    if ((lane & 15) == 0) {
      int g = lane >> 4;
      int rr = r0 + ((g & 1) << 1) + (g >> 1);
      if (rr < 277) a1v[rr] = act1_b[rr] + u;
    }
  }
  __syncthreads();

  // ---- phase 15: outputs ----
  if (wid < 5) {
    const float* wr = linact_w + (size_t)wid * 277;
    float p = 0.f;
    for (int j = lane; j < 277; j += 64) p = fmaf(wr[j], a1v[j], p);
    #pragma unroll
    for (int off = 32; off > 0; off >>= 1) p += __shfl_xor(p, off, 64);
    if (lane == 0) out[b * 26 + 21 + wid] = linact_b[wid] + p;
  }
  if (tid == 0) out[b * 26] = dTv;
  if (tid < 20) out[b * 26 + 1 + tid] = s.znv[tid];
}

// ---------- launcher ----------

extern "C" void kernel_launch(void* const* d_in, const int* in_sizes, int n_in,
                              void* d_out, int out_size, void* d_ws, size_t ws_size,
                              hipStream_t stream) {
  (void)in_sizes; (void)n_in; (void)out_size; (void)ws_size;
  const int*   X        = (const int*)  d_in[0];
  const float* emb_act  = (const float*)d_in[1];
  const float* emb_zone = (const float*)d_in[2];
  const float* lin0_w   = (const float*)d_in[3];
  const float* lin0_b   = (const float*)d_in[4];
  const float* qkv_w    = (const float*)d_in[5];
  const float* qkv_b    = (const float*)d_in[6];
  const float* attn_o_w = (const float*)d_in[7];
  const float* attn_o_b = (const float*)d_in[8];
  const float* ln1_g    = (const float*)d_in[9];
  const float* ln1_b    = (const float*)d_in[10];
  const float* ff1_w    = (const float*)d_in[11];
  const float* ff1_b    = (const float*)d_in[12];
  const float* ff2_w    = (const float*)d_in[13];
  const float* ff2_b    = (const float*)d_in[14];
  const float* ln2_g    = (const float*)d_in[15];
  const float* ln2_b    = (const float*)d_in[16];
  const float* relu_w   = (const float*)d_in[17];
  const float* relu_b   = (const float*)d_in[18];
  const float* dT_w     = (const float*)d_in[19];
  const float* dT_b     = (const float*)d_in[20];
  const float* lindT_w  = (const float*)d_in[21];
  const float* lindT_b  = (const float*)d_in[22];
  const float* zn_w     = (const float*)d_in[23];
  const float* zn_b     = (const float*)d_in[24];
  const float* linzn_w  = (const float*)d_in[25];
  const float* linzn_b  = (const float*)d_in[26];
  const float* act0_w   = (const float*)d_in[27];
  const float* act0_b   = (const float*)d_in[28];
  const float* act1_w   = (const float*)d_in[29];
  const float* act1_b   = (const float*)d_in[30];
  const float* linact_w = (const float*)d_in[31];
  const float* linact_b = (const float*)d_in[32];
  float* out = (float*)d_out;
  ushort* w16 = (ushort*)d_ws;   // needs 2.28 MB of workspace

  cvt_weights<<<dim3((CVT_TOTAL + 511) / 512), dim3(512), 0, stream>>>(
      qkv_w, attn_o_w, ff1_w, ff2_w, relu_w, dT_w, zn_w, act0_w, act1_w, w16);

  nmstpp_fused<<<dim3(BATCH), dim3(NT), 0, stream>>>(
      X, emb_act, emb_zone, lin0_w, lin0_b, w16, qkv_b, attn_o_b,
      ln1_g, ln1_b, ff1_b, ff2_b, ln2_g, ln2_b,
      relu_b, dT_b, lindT_w, lindT_b, zn_b,
      linzn_w, linzn_b, act0_b, act1_b, linact_w, linact_b,
      out);
}